// Round 8
// baseline (662.658 us; speedup 1.0000x reference)
//
#include <hip/hip_runtime.h>
#include <hip/hip_bf16.h>

#define B_   32
#define H_   128
#define W_   128
#define HW_  16384
#define C1_  128

typedef __attribute__((ext_vector_type(8))) short short8;
typedef __attribute__((ext_vector_type(4))) short short4v;
typedef __attribute__((ext_vector_type(4))) float f32x4;
typedef __attribute__((ext_vector_type(2))) float f32x2;

static __device__ __forceinline__ unsigned short bfbits(float f) {
    __hip_bfloat16 h = __float2bfloat16(f);
    return *reinterpret_cast<unsigned short*>(&h);
}
static __device__ __forceinline__ float bf2f(unsigned int u) {
    union { unsigned int ui; float f; } cv; cv.ui = u << 16; return cv.f;
}
static __device__ __forceinline__ unsigned short bftrunc(float f) {
    unsigned u = __builtin_bit_cast(unsigned, f);
    return (unsigned short)((u + 0x8000u) >> 16);
}

// ---- merged prep: w2t2 (with co-slot swizzle), w1t, zero stats ----
// w2t2 layout: [cc][kk][kg][slot][8], slot = (co + 2*kg) & 127  (bank spread for af reads)
__global__ __launch_bounds__(256) void prep_all(const float* __restrict__ w2,
                                                const float* __restrict__ w1,
                                                unsigned short* __restrict__ w2t2,
                                                unsigned short* __restrict__ w1t,
                                                float* __restrict__ st) {
    int idx = blockIdx.x * 256 + threadIdx.x;
    if (idx < 147456) {
        int e    = idx & 7;
        int slot = (idx >> 3) & 127;
        int kg   = (idx >> 10) & 3;
        int t    = idx >> 12;          // 0..35
        int kk = t % 9, cc = t / 9;
        int co = (slot - 2 * kg) & 127;
        int ci = cc * 32 + kg * 8 + e;
        w2t2[idx] = bfbits(w2[((size_t)co * 128 + ci) * 9 + kk]);
    } else if (idx < 151552) {
        int i2 = idx - 147456;
        int k = i2 & 31, ci = i2 >> 5;
        w1t[i2] = (k < 18) ? bfbits(w1[ci * 18 + k]) : (unsigned short)0;
    } else if (idx < 152064) {
        st[idx - 151552] = 0.f;
    }
}

// ---------------- gaussian splat: both passes in LDS, one block per image ----------------
__global__ __launch_bounds__(256) void gauss_k(const float* __restrict__ jmap,
                                               float* __restrict__ outg,
                                               const float* __restrict__ ga,
                                               const float* __restrict__ gb) {
    __shared__ float mk[16384];
    __shared__ float vb[16384];
    __shared__ float k1[33];
    int b = blockIdx.x;
    int tid = threadIdx.x;
    float a = ga[0] / (gb[0] * gb[0]);
    if (tid < 33) { float d = (float)tid - 16.f; k1[tid] = expf(a * d * d); }
    const float* src = jmap + (size_t)b * HW_;
    for (int i = tid; i < 16384; i += 256) mk[i] = src[i];
    __syncthreads();
    int x = tid & 127;
    int ybase = (tid >> 7) * 64;
    for (int yy = 0; yy < 64; ++yy) {
        int y = ybase + yy;
        int lo = y - 16; if (lo < 0) lo = 0;
        int hi = y + 16; if (hi > 127) hi = 127;
        float s = 0.f;
        for (int d = lo; d <= hi; ++d)
            s += (mk[d * 128 + x] == 1.0f) ? k1[d - y + 16] : 0.f;
        vb[y * 128 + x] = s;
    }
    __syncthreads();
    int lo = x - 16; if (lo < 0) lo = 0;
    int hi = x + 16; if (hi > 127) hi = 127;
    for (int yy = 0; yy < 64; ++yy) {
        int y = ybase + yy;
        float s = 0.f;
        for (int d = lo; d <= hi; ++d)
            s += k1[d - x + 16] * vb[y * 128 + d];
        float g = mk[y * 128 + x] + s;
        g = (g <= 0.05f) ? 0.f : fminf(g, 1.0f);
        outg[(size_t)b * HW_ + y * 128 + x] = g;
    }
}

// ---------------- conv1 stats only (exact f32) ----------------
__global__ __launch_bounds__(256) void conv1stats_k(const float* __restrict__ out5,
                                                    const float* __restrict__ w1,
                                                    const float* __restrict__ b1,
                                                    float* __restrict__ sum1,
                                                    float* __restrict__ sq1) {
    int cg = blockIdx.x;
    int b  = blockIdx.y;
    int tid = threadIdx.x;
    __shared__ float wsh[8][18];
    __shared__ float bsh[8];
    __shared__ float red[256];
    for (int i = tid; i < 144; i += 256) wsh[i / 18][i % 18] = w1[cg * 8 * 18 + i];
    if (tid < 8) bsh[tid] = b1[cg * 8 + tid];
    __syncthreads();
    float ls[8], lq[8];
    #pragma unroll
    for (int i = 0; i < 8; ++i) { ls[i] = 0.f; lq[i] = 0.f; }
    const float* in0 = out5 + (size_t)b * 5 * HW_;
    const float* in1 = in0 + HW_;
    for (int pos = tid; pos < HW_; pos += 256) {
        int y = pos >> 7, x = pos & 127;
        float v0[9], v1[9];
        #pragma unroll
        for (int ky = 0; ky < 3; ++ky)
            #pragma unroll
            for (int kx = 0; kx < 3; ++kx) {
                int yy = y + ky - 1, xx = x + kx - 1;
                bool ok = ((unsigned)yy < 128u) && ((unsigned)xx < 128u);
                v0[ky * 3 + kx] = ok ? in0[yy * W_ + xx] : 0.f;
                v1[ky * 3 + kx] = ok ? in1[yy * W_ + xx] : 0.f;
            }
        #pragma unroll
        for (int i = 0; i < 8; ++i) {
            float a = bsh[i];
            #pragma unroll
            for (int k = 0; k < 9; ++k) a += v0[k] * wsh[i][k] + v1[k] * wsh[i][9 + k];
            ls[i] += a; lq[i] += a * a;
        }
    }
    for (int i = 0; i < 8; ++i) {
        red[tid] = ls[i]; __syncthreads();
        for (int s = 128; s > 0; s >>= 1) { if (tid < s) red[tid] += red[tid + s]; __syncthreads(); }
        if (tid == 0) atomicAdd(&sum1[cg * 8 + i], red[0]);
        __syncthreads();
        red[tid] = lq[i]; __syncthreads();
        for (int s = 128; s > 0; s >>= 1) { if (tid < s) red[tid] += red[tid + s]; __syncthreads(); }
        if (tid == 0) atomicAdd(&sq1[cg * 8 + i], red[0]);
        __syncthreads();
    }
}

// ---------------- BN params ----------------
__global__ void bnp_k(const float* __restrict__ sum, const float* __restrict__ sq,
                      const float* __restrict__ gamma, const float* __restrict__ beta,
                      float* __restrict__ s, float* __restrict__ t) {
    int c = threadIdx.x;
    const float N = (float)(B_ * HW_);
    float m = sum[c] / N;
    float v = sq[c] / N - m * m;
    float sc = gamma[c] / sqrtf(v + 1e-5f);
    s[c] = sc;
    t[c] = beta[c] - sc * m;
}

// ---------------- conv2 via MFMA: 1024-thr block, co128 x pos512 (4 rows) ----------------
// r6 structure + weight double-buffer (5-tap / 4-tap chunks via global_load_lds, every
// DMA drained one full MFMA phase after issue) + co-slot swizzle on af reads.
__global__ __launch_bounds__(1024) void conv2_mfma(
    const float* __restrict__ out5,
    const float* __restrict__ b1,
    const float* __restrict__ s1,
    const float* __restrict__ t1,
    const unsigned short* __restrict__ w2t2,
    const unsigned short* __restrict__ w1t,
    const float* __restrict__ b2,
    __hip_bfloat16* __restrict__ y2,
    float* __restrict__ sum2,
    float* __restrict__ sq2)
{
    __shared__ unsigned short inT[31200];        // h1: [r*130+c][40] (6 rows), 62400 B
    __shared__ unsigned short wring[2][20480];   // buf0: taps0-4 (40960B), buf1: taps5-8
    __shared__ unsigned short w1l[4096];         // conv1 weights [ci][32]
    __shared__ float s1sh[128], t1sh[128], redS[128], redQ[128];

    const int tid = threadIdx.x;
    const int b  = blockIdx.x >> 5;
    const int y0 = (blockIdx.x & 31) * 4;
    const int lane = tid & 63, w = tid >> 6;   // w 0..15
    const int wm = w & 1, wn = w >> 1;         // co half / pos 64-group
    const int l15 = lane & 15, kg = lane >> 4;

    if (tid < 128) {
        redS[tid] = 0.f; redQ[tid] = 0.f;
        float sv = s1[tid]; s1sh[tid] = sv;
        t1sh[tid] = fmaf(sv, b1[tid], t1[tid]);   // fold conv1 bias into BN shift
    }
    if (tid < 512) *(short8*)&w1l[tid * 8] = *(const short8*)&w1t[tid * 8];

    // issue DMA: chunkA(cc=0) = taps 0..4 into buf0 (hidden under bfrag prologue)
    {
        const unsigned short* src = w2t2;
        __builtin_amdgcn_global_load_lds((const unsigned int*)(src + tid * 8),
                                         (unsigned int*)&wring[0][tid * 8], 16, 0, 0);
        __builtin_amdgcn_global_load_lds((const unsigned int*)(src + (1024 + tid) * 8),
                                         (unsigned int*)&wring[0][(1024 + tid) * 8], 16, 0, 0);
        if (tid < 512)
            __builtin_amdgcn_global_load_lds((const unsigned int*)(src + (2048 + tid) * 8),
                                             (unsigned int*)&wring[0][(2048 + tid) * 8], 16, 0, 0);
    }

    // ---- prebuild h1 im2col B-fragments in registers (once) ----
    const float* in0 = out5 + (size_t)b * 5 * HW_;
    const float* in1 = in0 + HW_;
    const int mi  = wm;        // wave's conv1 ci-half
    const int njb = w >> 1;    // base position-tile
    short8 bfrag[7];
    #pragma unroll
    for (int k = 0; k < 7; ++k) {
        short8 f = (short8){0,0,0,0,0,0,0,0};
        int nj = njb + k * 8;
        int q  = nj * 16 + l15;
        if (nj <= 48 && q < 780) {
            int r = q / 130, c = q - r * 130;
            int gy = y0 - 1 + r, gx = c - 1;
            #pragma unroll
            for (int kk = 0; kk < 8; ++kk) {
                int kidx = kg * 8 + kk;
                unsigned short v = 0;
                if (kidx < 18) {
                    int ch = (kidx >= 9) ? 1 : 0;
                    int km = kidx - ch * 9;
                    int ky = km / 3, kx = km - ky * 3;
                    int yy = gy + ky - 1, xx = gx + kx - 1;
                    if ((unsigned)yy < 128u && (unsigned)xx < 128u)
                        v = bfbits((ch ? in1 : in0)[yy * W_ + xx]);
                }
                f[kk] = (short)v;
            }
        }
        bfrag[k] = f;
    }
    __syncthreads();   // prm/w1l visible; chunkA(0) DMA drained

    f32x4 acc[4][4];
    #pragma unroll
    for (int fm = 0; fm < 4; ++fm)
        #pragma unroll
        for (int fn = 0; fn < 4; ++fn) acc[fm][fn] = (f32x4){0.f, 0.f, 0.f, 0.f};

    for (int cc = 0; cc < 4; ++cc) {
        // ---- h1 phase: conv1+BN1+ReLU via MFMA from register B-frags ----
        short8 a1 = *(const short8*)&w1l[(cc * 32 + mi * 16 + l15) * 32 + kg * 8];
        #pragma unroll
        for (int k = 0; k < 7; ++k) {
            int nj = njb + k * 8;
            if (nj <= 48) {
                int q = nj * 16 + l15;
                f32x4 hacc = (f32x4){0.f, 0.f, 0.f, 0.f};
                hacc = __builtin_amdgcn_mfma_f32_16x16x32_bf16(a1, bfrag[k], hacc, 0, 0, 0);
                int r = q / 130, c = q - r * 130;
                int gy = y0 - 1 + r;
                bool zero = (q >= 780) || ((unsigned)gy >= 128u) || (c == 0) || (c == 129);
                short4v hv;
                #pragma unroll
                for (int rr = 0; rr < 4; ++rr) {
                    int cig = cc * 32 + mi * 16 + kg * 4 + rr;
                    float h = fmaxf(fmaf(s1sh[cig], hacc[rr], t1sh[cig]), 0.f);
                    hv[rr] = zero ? (short)0 : (short)bfbits(h);
                }
                if (q < 780)
                    *(short4v*)&inT[(r * 130 + c) * 40 + mi * 16 + kg * 4] = hv;
            }
        }
        __syncthreads();   // B1: inT ready (no DMA outstanding here)

        // issue chunkB(cc) = taps 5..8 into buf1 (lands under chunkA MFMAs)
        {
            const unsigned short* src = w2t2 + cc * 36864 + 20480;
            __builtin_amdgcn_global_load_lds((const unsigned int*)(src + tid * 8),
                                             (unsigned int*)&wring[1][tid * 8], 16, 0, 0);
            __builtin_amdgcn_global_load_lds((const unsigned int*)(src + (1024 + tid) * 8),
                                             (unsigned int*)&wring[1][(1024 + tid) * 8], 16, 0, 0);
        }
        // ---- chunkA: taps 0..4 from buf0 ----
        #pragma unroll
        for (int t2 = 0; t2 < 5; ++t2) {
            const int kk = t2;
            const int ky = kk / 3, kx = kk - (kk / 3) * 3;
            short8 af[4], bv[4];
            #pragma unroll
            for (int fm = 0; fm < 4; ++fm)
                af[fm] = *(const short8*)&wring[0][((t2 * 4 + kg) * 128 +
                          ((wm * 64 + fm * 16 + l15 + 2 * kg) & 127)) * 8];
            #pragma unroll
            for (int fn = 0; fn < 4; ++fn) {
                int n = wn * 64 + fn * 16 + l15;
                int r2 = (n >> 7) + ky, c2 = (n & 127) + kx;
                bv[fn] = *(const short8*)&inT[(r2 * 130 + c2) * 40 + kg * 8];
            }
            #pragma unroll
            for (int fm = 0; fm < 4; ++fm)
                #pragma unroll
                for (int fn = 0; fn < 4; ++fn)
                    acc[fm][fn] = __builtin_amdgcn_mfma_f32_16x16x32_bf16(af[fm], bv[fn], acc[fm][fn], 0, 0, 0);
        }
        __syncthreads();   // B2: chunkB(cc) drained; buf0 free

        // issue chunkA(cc+1) into buf0 (lands under chunkB MFMAs)
        if (cc < 3) {
            const unsigned short* src = w2t2 + (cc + 1) * 36864;
            __builtin_amdgcn_global_load_lds((const unsigned int*)(src + tid * 8),
                                             (unsigned int*)&wring[0][tid * 8], 16, 0, 0);
            __builtin_amdgcn_global_load_lds((const unsigned int*)(src + (1024 + tid) * 8),
                                             (unsigned int*)&wring[0][(1024 + tid) * 8], 16, 0, 0);
            if (tid < 512)
                __builtin_amdgcn_global_load_lds((const unsigned int*)(src + (2048 + tid) * 8),
                                                 (unsigned int*)&wring[0][(2048 + tid) * 8], 16, 0, 0);
        }
        // ---- chunkB: taps 5..8 from buf1 ----
        #pragma unroll
        for (int t2 = 0; t2 < 4; ++t2) {
            const int kk = 5 + t2;
            const int ky = kk / 3, kx = kk - (kk / 3) * 3;
            short8 af[4], bv[4];
            #pragma unroll
            for (int fm = 0; fm < 4; ++fm)
                af[fm] = *(const short8*)&wring[1][((t2 * 4 + kg) * 128 +
                          ((wm * 64 + fm * 16 + l15 + 2 * kg) & 127)) * 8];
            #pragma unroll
            for (int fn = 0; fn < 4; ++fn) {
                int n = wn * 64 + fn * 16 + l15;
                int r2 = (n >> 7) + ky, c2 = (n & 127) + kx;
                bv[fn] = *(const short8*)&inT[(r2 * 130 + c2) * 40 + kg * 8];
            }
            #pragma unroll
            for (int fm = 0; fm < 4; ++fm)
                #pragma unroll
                for (int fn = 0; fn < 4; ++fn)
                    acc[fm][fn] = __builtin_amdgcn_mfma_f32_16x16x32_bf16(af[fm], bv[fn], acc[fm][fn], 0, 0, 0);
        }
        __syncthreads();   // B3: chunkA(cc+1) drained; buf1 free; inT rewrite safe
    }

    // ---- epilogue: stats + coalesced y2 via LDS repack (pt = wring region) ----
    unsigned short* pt = &wring[0][0];
    #pragma unroll
    for (int fm = 0; fm < 4; ++fm)
        #pragma unroll
        for (int r = 0; r < 4; ++r) {
            const int co = wm * 64 + fm * 16 + kg * 4 + r;
            const float bb = b2[co];
            float ls = 0.f, lq = 0.f;
            #pragma unroll
            for (int fn = 0; fn < 4; ++fn) { float v = acc[fm][fn][r] + bb; ls += v; lq += v * v; }
            #pragma unroll
            for (int m = 1; m < 16; m <<= 1) {
                ls += __shfl_xor(ls, m, 64);
                lq += __shfl_xor(lq, m, 64);
            }
            if (l15 == 0) { atomicAdd(&redS[co], ls); atomicAdd(&redQ[co], lq); }
        }
    if (wm == 0) {
        #pragma unroll
        for (int fm = 0; fm < 4; ++fm)
            #pragma unroll
            for (int r = 0; r < 4; ++r) {
                const int col = fm * 16 + kg * 4 + r;
                const float bb = b2[col];
                const int xr = ((col >> 2) & 3) << 4;
                #pragma unroll
                for (int fn = 0; fn < 4; ++fn) {
                    int n = wn * 64 + fn * 16 + l15;
                    pt[col * 512 + (n ^ xr)] = bftrunc(acc[fm][fn][r] + bb);
                }
            }
    }
    __syncthreads();
    if (tid < 128) { atomicAdd(&sum2[tid], redS[tid]); atomicAdd(&sq2[tid], redQ[tid]); }
    {
        unsigned short* y2u = (unsigned short*)y2;
        int co_l = tid >> 4, sub = tid & 15;
        int xr = ((co_l >> 2) & 3) << 4;
        size_t base = (((size_t)b * C1_ + co_l) * H_ + y0) * (size_t)W_ + sub * 8;
        #pragma unroll
        for (int j = 0; j < 4; ++j) {
            int p = j * 128 + sub * 8;
            *(short8*)&y2u[base + (size_t)j * W_] = *(short8*)&pt[co_l * 512 + (p ^ xr)];
        }
    }
    __syncthreads();
    if (wm == 1) {
        #pragma unroll
        for (int fm = 0; fm < 4; ++fm)
            #pragma unroll
            for (int r = 0; r < 4; ++r) {
                const int col = fm * 16 + kg * 4 + r;
                const float bb = b2[64 + col];
                const int xr = ((col >> 2) & 3) << 4;
                #pragma unroll
                for (int fn = 0; fn < 4; ++fn) {
                    int n = wn * 64 + fn * 16 + l15;
                    pt[col * 512 + (n ^ xr)] = bftrunc(acc[fm][fn][r] + bb);
                }
            }
    }
    __syncthreads();
    {
        unsigned short* y2u = (unsigned short*)y2;
        int co_l = tid >> 4, sub = tid & 15;
        int xr = ((co_l >> 2) & 3) << 4;
        size_t base = (((size_t)b * C1_ + 64 + co_l) * H_ + y0) * (size_t)W_ + sub * 8;
        #pragma unroll
        for (int j = 0; j < 4; ++j) {
            int p = j * 128 + sub * 8;
            *(short8*)&y2u[base + (size_t)j * W_] = *(short8*)&pt[co_l * 512 + (p ^ xr)];
        }
    }
}

// ---------------- lateral path: maxpool2 + conv3x3(2->2) pad1 ----------------
__global__ __launch_bounds__(256) void poolconv_k(const float* __restrict__ out5,
                                                  const float* __restrict__ wl,
                                                  const float* __restrict__ bl,
                                                  float* __restrict__ ds) {
    int idx = blockIdx.x * 256 + threadIdx.x;
    int j = idx & 63;
    int i = (idx >> 6) & 63;
    int c = (idx >> 12) & 1;
    int b = idx >> 13;
    float acc = bl[c];
    #pragma unroll
    for (int ci = 0; ci < 2; ++ci) {
        const float* in = out5 + ((size_t)b * 5 + ci) * HW_;
        #pragma unroll
        for (int ky = 0; ky < 3; ++ky) {
            int ii = i + ky - 1;
            if (ii < 0 || ii > 63) continue;
            #pragma unroll
            for (int kx = 0; kx < 3; ++kx) {
                int jj = j + kx - 1;
                if (jj < 0 || jj > 63) continue;
                const float* p = in + (2 * ii) * W_ + 2 * jj;
                float pooled = fmaxf(fmaxf(p[0], p[1]), fmaxf(p[W_], p[W_ + 1]));
                acc += pooled * wl[(c * 2 + ci) * 9 + ky * 3 + kx];
            }
        }
    }
    ds[idx] = acc;
}

// ---------------- final: conv1x1(BN2+ReLU) + upsample + softmax + sigmoids, 2 px/thr ----
__global__ __launch_bounds__(256) void final_k(const float* __restrict__ out5,
                                               const __hip_bfloat16* __restrict__ y2,
                                               const float* __restrict__ s2,
                                               const float* __restrict__ t2,
                                               const float* __restrict__ w3,
                                               const float* __restrict__ b3,
                                               const float* __restrict__ dsb,
                                               float* __restrict__ out) {
    __shared__ float w3s[256], s2s[128], t2s[128];
    int tid = threadIdx.x;
    w3s[tid] = w3[tid];
    if (tid < 128) { s2s[tid] = s2[tid]; t2s[tid] = t2[tid]; }
    __syncthreads();
    int gid = blockIdx.x * 256 + tid;       // 262144 = 32*128*64
    int b = gid >> 13;
    int rem = gid & 8191;
    int y = rem >> 6;
    int x0 = (rem & 63) * 2;
    int p = y * W_ + x0;

    const unsigned short* yp = (const unsigned short*)y2 + (size_t)b * C1_ * HW_ + p;
    float jm0a = b3[0], jm1a = b3[1], jm0b = b3[0], jm1b = b3[1];
    for (int ci = 0; ci < 128; ++ci) {
        unsigned int v = *(const unsigned int*)(yp + (size_t)ci * HW_);
        float sc = s2s[ci], tc = t2s[ci];
        float w0 = w3s[ci], w1c = w3s[128 + ci];
        float h0 = fmaxf(fmaf(sc, bf2f(v & 0xffffu), tc), 0.f);
        float h1 = fmaxf(fmaf(sc, bf2f(v >> 16), tc), 0.f);
        jm0a = fmaf(h0, w0, jm0a); jm1a = fmaf(h0, w1c, jm1a);
        jm0b = fmaf(h1, w0, jm0b); jm1b = fmaf(h1, w1c, jm1b);
    }

    const float fo = (float)(63.0 / 127.0);
    float sy = (float)y * fo;
    int ly = (int)floorf(sy); ly = ly < 0 ? 0 : (ly > 62 ? 62 : ly);
    float wy = sy - (float)ly;
    const float* dbase = dsb + ((size_t)b * 2) * 4096;
    float sig[2];
    float jm0[2] = {jm0a, jm0b}, jm1[2] = {jm1a, jm1b};
    #pragma unroll
    for (int i = 0; i < 2; ++i) {
        int x = x0 + i;
        float sx = (float)x * fo;
        int lx = (int)floorf(sx); lx = lx < 0 ? 0 : (lx > 62 ? 62 : lx);
        float wx = sx - (float)lx;
        float up[2];
        #pragma unroll
        for (int c = 0; c < 2; ++c) {
            const float* d = dbase + c * 4096;
            float d00 = d[ly * 64 + lx],       d01 = d[ly * 64 + lx + 1];
            float d10 = d[(ly + 1) * 64 + lx], d11 = d[(ly + 1) * 64 + lx + 1];
            up[c] = (1.f - wy) * ((1.f - wx) * d00 + wx * d01) + wy * ((1.f - wx) * d10 + wx * d11);
        }
        float dlt = (jm1[i] + up[1]) - (jm0[i] + up[0]);
        sig[i] = 1.f / (1.f + expf(-dlt));
    }
    *(f32x2*)&out[(size_t)b * HW_ + p] = (f32x2){sig[0], sig[1]};

    float lm0 = out5[((size_t)b * 5 + 2) * HW_ + p];
    float lm1 = out5[((size_t)b * 5 + 2) * HW_ + p + 1];
    *(f32x2*)&out[524288 + (size_t)b * HW_ + p] =
        (f32x2){1.f / (1.f + expf(-lm0)), 1.f / (1.f + expf(-lm1))};

    float o30 = out5[((size_t)b * 5 + 3) * HW_ + p];
    float o31 = out5[((size_t)b * 5 + 3) * HW_ + p + 1];
    float o40 = out5[((size_t)b * 5 + 4) * HW_ + p];
    float o41 = out5[((size_t)b * 5 + 4) * HW_ + p + 1];
    *(f32x2*)&out[1048576 + ((size_t)b * 2 + 0) * HW_ + p] =
        (f32x2){1.f / (1.f + expf(-o30)) - 0.5f, 1.f / (1.f + expf(-o31)) - 0.5f};
    *(f32x2*)&out[1048576 + ((size_t)b * 2 + 1) * HW_ + p] =
        (f32x2){1.f / (1.f + expf(-o40)) - 0.5f, 1.f / (1.f + expf(-o41)) - 0.5f};
}

extern "C" void kernel_launch(void* const* d_in, const int* in_sizes, int n_in,
                              void* d_out, int out_size, void* d_ws, size_t ws_size,
                              hipStream_t stream) {
    const float* out5 = (const float*)d_in[0];
    const float* jmap = (const float*)d_in[1];
    const float* w1   = (const float*)d_in[2];
    const float* b1   = (const float*)d_in[3];
    const float* g1   = (const float*)d_in[4];
    const float* be1  = (const float*)d_in[5];
    const float* w2   = (const float*)d_in[6];
    const float* b2   = (const float*)d_in[7];
    const float* g2   = (const float*)d_in[8];
    const float* be2  = (const float*)d_in[9];
    const float* w3   = (const float*)d_in[10];
    const float* b3   = (const float*)d_in[11];
    const float* wl   = (const float*)d_in[12];
    const float* bl   = (const float*)d_in[13];
    const float* ga   = (const float*)d_in[14];
    const float* gb   = (const float*)d_in[15];
    float* out = (float*)d_out;

    // ws layout (~135.3 MB):
    //   [0, 134217728)           y2 bf16
    //   [134217728, +294912)     w2t2 } overlapped later by dsb (disjoint lifetimes)
    //   [134512640, +8192)       w1t  }
    //   [134217728, +1048576)    dsb (poolconv out; written after conv2 done)
    //   [135266304, +4096)       stats
    char* ws = (char*)d_ws;
    __hip_bfloat16* y2 = (__hip_bfloat16*)ws;
    unsigned short* w2t2 = (unsigned short*)(ws + 134217728);
    unsigned short* w1t  = (unsigned short*)(ws + 134512640);
    float* dsb = (float*)(ws + 134217728);
    float* st  = (float*)(ws + 135266304);
    float* sum1 = st;        float* sq1 = st + 128;
    float* sum2 = st + 256;  float* sq2 = st + 384;
    float* s1 = st + 512;    float* t1 = st + 640;
    float* s2 = st + 768;    float* t2 = st + 896;

    float* gtmp = out + 2097152;   // gauss target region of d_out

    prep_all<<<594, 256, 0, stream>>>(w2, w1, w2t2, w1t, st);
    gauss_k<<<32, 256, 0, stream>>>(jmap, gtmp, ga, gb);
    conv1stats_k<<<dim3(16, 32), 256, 0, stream>>>(out5, w1, b1, sum1, sq1);
    bnp_k<<<1, 128, 0, stream>>>(sum1, sq1, g1, be1, s1, t1);
    conv2_mfma<<<1024, 1024, 0, stream>>>(out5, b1, s1, t1, w2t2, w1t, b2, y2, sum2, sq2);
    bnp_k<<<1, 128, 0, stream>>>(sum2, sq2, g2, be2, s2, t2);
    poolconv_k<<<1024, 256, 0, stream>>>(out5, wl, bl, dsb);
    final_k<<<1024, 256, 0, stream>>>(out5, y2, s2, t2, w3, b3, dsb, out);
}

// Round 9
// 580.215 us; speedup vs baseline: 1.1421x; 1.1421x over previous
//
#include <hip/hip_runtime.h>
#include <hip/hip_bf16.h>

#define B_   32
#define H_   128
#define W_   128
#define HW_  16384
#define C1_  128

typedef __attribute__((ext_vector_type(8))) short short8;
typedef __attribute__((ext_vector_type(4))) short short4v;
typedef __attribute__((ext_vector_type(4))) float f32x4;
typedef __attribute__((ext_vector_type(2))) float f32x2;

static __device__ __forceinline__ unsigned short bfbits(float f) {
    __hip_bfloat16 h = __float2bfloat16(f);
    return *reinterpret_cast<unsigned short*>(&h);
}
static __device__ __forceinline__ float bf2f(unsigned int u) {
    union { unsigned int ui; float f; } cv; cv.ui = u << 16; return cv.f;
}

// ---- merged prep: w2t2 (r6 layout, NO swizzle), w1t, zero stats ----
__global__ __launch_bounds__(256) void prep_all(const float* __restrict__ w2,
                                                const float* __restrict__ w1,
                                                unsigned short* __restrict__ w2t2,
                                                unsigned short* __restrict__ w1t,
                                                float* __restrict__ st) {
    int idx = blockIdx.x * 256 + threadIdx.x;
    if (idx < 147456) {
        int e  = idx & 7;
        int co = (idx >> 3) & 127;
        int kg = (idx >> 10) & 3;
        int t  = idx >> 12;          // 0..35
        int kk = t % 9, cc = t / 9;
        int ci = cc * 32 + kg * 8 + e;
        w2t2[idx] = bfbits(w2[((size_t)co * 128 + ci) * 9 + kk]);
    } else if (idx < 151552) {
        int i2 = idx - 147456;
        int k = i2 & 31, ci = i2 >> 5;
        w1t[i2] = (k < 18) ? bfbits(w1[ci * 18 + k]) : (unsigned short)0;
    } else if (idx < 152064) {
        st[idx - 151552] = 0.f;
    }
}

// ---------------- gaussian splat: both passes in LDS, one block per image ----------------
__global__ __launch_bounds__(256) void gauss_k(const float* __restrict__ jmap,
                                               float* __restrict__ outg,
                                               const float* __restrict__ ga,
                                               const float* __restrict__ gb) {
    __shared__ float mk[16384];
    __shared__ float vb[16384];
    __shared__ float k1[33];
    int b = blockIdx.x;
    int tid = threadIdx.x;
    float a = ga[0] / (gb[0] * gb[0]);
    if (tid < 33) { float d = (float)tid - 16.f; k1[tid] = expf(a * d * d); }
    const float* src = jmap + (size_t)b * HW_;
    for (int i = tid; i < 16384; i += 256) mk[i] = src[i];
    __syncthreads();
    int x = tid & 127;
    int ybase = (tid >> 7) * 64;
    for (int yy = 0; yy < 64; ++yy) {
        int y = ybase + yy;
        int lo = y - 16; if (lo < 0) lo = 0;
        int hi = y + 16; if (hi > 127) hi = 127;
        float s = 0.f;
        for (int d = lo; d <= hi; ++d)
            s += (mk[d * 128 + x] == 1.0f) ? k1[d - y + 16] : 0.f;
        vb[y * 128 + x] = s;
    }
    __syncthreads();
    int lo = x - 16; if (lo < 0) lo = 0;
    int hi = x + 16; if (hi > 127) hi = 127;
    for (int yy = 0; yy < 64; ++yy) {
        int y = ybase + yy;
        float s = 0.f;
        for (int d = lo; d <= hi; ++d)
            s += k1[d - x + 16] * vb[y * 128 + d];
        float g = mk[y * 128 + x] + s;
        g = (g <= 0.05f) ? 0.f : fminf(g, 1.0f);
        outg[(size_t)b * HW_ + y * 128 + x] = g;
    }
}

// ---------------- conv1 stats only (exact f32) ----------------
__global__ __launch_bounds__(256) void conv1stats_k(const float* __restrict__ out5,
                                                    const float* __restrict__ w1,
                                                    const float* __restrict__ b1,
                                                    float* __restrict__ sum1,
                                                    float* __restrict__ sq1) {
    int cg = blockIdx.x;
    int b  = blockIdx.y;
    int tid = threadIdx.x;
    __shared__ float wsh[8][18];
    __shared__ float bsh[8];
    __shared__ float red[256];
    for (int i = tid; i < 144; i += 256) wsh[i / 18][i % 18] = w1[cg * 8 * 18 + i];
    if (tid < 8) bsh[tid] = b1[cg * 8 + tid];
    __syncthreads();
    float ls[8], lq[8];
    #pragma unroll
    for (int i = 0; i < 8; ++i) { ls[i] = 0.f; lq[i] = 0.f; }
    const float* in0 = out5 + (size_t)b * 5 * HW_;
    const float* in1 = in0 + HW_;
    for (int pos = tid; pos < HW_; pos += 256) {
        int y = pos >> 7, x = pos & 127;
        float v0[9], v1[9];
        #pragma unroll
        for (int ky = 0; ky < 3; ++ky)
            #pragma unroll
            for (int kx = 0; kx < 3; ++kx) {
                int yy = y + ky - 1, xx = x + kx - 1;
                bool ok = ((unsigned)yy < 128u) && ((unsigned)xx < 128u);
                v0[ky * 3 + kx] = ok ? in0[yy * W_ + xx] : 0.f;
                v1[ky * 3 + kx] = ok ? in1[yy * W_ + xx] : 0.f;
            }
        #pragma unroll
        for (int i = 0; i < 8; ++i) {
            float a = bsh[i];
            #pragma unroll
            for (int k = 0; k < 9; ++k) a += v0[k] * wsh[i][k] + v1[k] * wsh[i][9 + k];
            ls[i] += a; lq[i] += a * a;
        }
    }
    for (int i = 0; i < 8; ++i) {
        red[tid] = ls[i]; __syncthreads();
        for (int s = 128; s > 0; s >>= 1) { if (tid < s) red[tid] += red[tid + s]; __syncthreads(); }
        if (tid == 0) atomicAdd(&sum1[cg * 8 + i], red[0]);
        __syncthreads();
        red[tid] = lq[i]; __syncthreads();
        for (int s = 128; s > 0; s >>= 1) { if (tid < s) red[tid] += red[tid + s]; __syncthreads(); }
        if (tid == 0) atomicAdd(&sq1[cg * 8 + i], red[0]);
        __syncthreads();
    }
}

// ---------------- BN params ----------------
__global__ void bnp_k(const float* __restrict__ sum, const float* __restrict__ sq,
                      const float* __restrict__ gamma, const float* __restrict__ beta,
                      float* __restrict__ s, float* __restrict__ t) {
    int c = threadIdx.x;
    const float N = (float)(B_ * HW_);
    float m = sum[c] / N;
    float v = sq[c] / N - m * m;
    float sc = gamma[c] / sqrtf(v + 1e-5f);
    s[c] = sc;
    t[c] = beta[c] - sc * m;
}

// ---------------- conv2 via MFMA: GOLDEN r6 version (256 us, FETCH 41.6 MB) ----------------
// 1024-thr block, co128 x pos512 (4 rows). Per cc: single 9-tap DMA burst + h1 phase
// (register B-frags) + 1 barrier + 9-tap MFMA + 1 barrier.
__global__ __launch_bounds__(1024) void conv2_mfma(
    const float* __restrict__ out5,
    const float* __restrict__ b1,
    const float* __restrict__ s1,
    const float* __restrict__ t1,
    const unsigned short* __restrict__ w2t2,
    const unsigned short* __restrict__ w1t,
    const float* __restrict__ b2,
    __hip_bfloat16* __restrict__ y2,
    float* __restrict__ sum2,
    float* __restrict__ sq2)
{
    __shared__ unsigned short inT[31200];   // h1: [r*130+c][40] (6 rows), 62400 B
    __shared__ unsigned short wc[36864];    // all 9 taps of one cc, 73728 B; reused as pt
    __shared__ unsigned short w1l[4096];    // conv1 weights [ci][32], 8192 B
    __shared__ float s1sh[128], t1sh[128], redS[128], redQ[128];

    const int tid = threadIdx.x;
    const int b  = blockIdx.x >> 5;
    const int y0 = (blockIdx.x & 31) * 4;
    const int lane = tid & 63, w = tid >> 6;   // w 0..15
    const int wm = w & 1, wn = w >> 1;         // co half / pos 64-group
    const int l15 = lane & 15, kg = lane >> 4;

    if (tid < 128) {
        redS[tid] = 0.f; redQ[tid] = 0.f;
        float sv = s1[tid]; s1sh[tid] = sv;
        t1sh[tid] = fmaf(sv, b1[tid], t1[tid]);   // fold conv1 bias into BN shift
    }
    if (tid < 512) *(short8*)&w1l[tid * 8] = *(const short8*)&w1t[tid * 8];

    // ---- prebuild h1 im2col B-fragments in registers (once) ----
    const float* in0 = out5 + (size_t)b * 5 * HW_;
    const float* in1 = in0 + HW_;
    const int mi  = wm;        // wave's conv1 ci-half
    const int njb = w >> 1;    // base position-tile
    short8 bfrag[7];
    #pragma unroll
    for (int k = 0; k < 7; ++k) {
        short8 f = (short8){0,0,0,0,0,0,0,0};
        int nj = njb + k * 8;
        int q  = nj * 16 + l15;
        if (nj <= 48 && q < 780) {
            int r = q / 130, c = q - r * 130;
            int gy = y0 - 1 + r, gx = c - 1;
            #pragma unroll
            for (int kk = 0; kk < 8; ++kk) {
                int kidx = kg * 8 + kk;
                unsigned short v = 0;
                if (kidx < 18) {
                    int ch = (kidx >= 9) ? 1 : 0;
                    int km = kidx - ch * 9;
                    int ky = km / 3, kx = km - ky * 3;
                    int yy = gy + ky - 1, xx = gx + kx - 1;
                    if ((unsigned)yy < 128u && (unsigned)xx < 128u)
                        v = bfbits((ch ? in1 : in0)[yy * W_ + xx]);
                }
                f[kk] = (short)v;
            }
        }
        bfrag[k] = f;
    }
    __syncthreads();   // w1l / s1sh / red zero visible

    f32x4 acc[4][4];
    #pragma unroll
    for (int fm = 0; fm < 4; ++fm)
        #pragma unroll
        for (int fn = 0; fn < 4; ++fn) acc[fm][fn] = (f32x4){0.f, 0.f, 0.f, 0.f};

    for (int cc = 0; cc < 4; ++cc) {
        // async stage all 9 taps' weights for this cc into wc (drained by next barrier)
        const unsigned short* wsrc = w2t2 + cc * 36864;
        #pragma unroll
        for (int u = 0; u < 4; ++u)
            __builtin_amdgcn_global_load_lds(
                (const unsigned int*)(wsrc + (u * 1024 + tid) * 8),
                (unsigned int*)&wc[(u * 1024 + tid) * 8], 16, 0, 0);
        if (tid < 512)
            __builtin_amdgcn_global_load_lds(
                (const unsigned int*)(wsrc + (4096 + tid) * 8),
                (unsigned int*)&wc[(4096 + tid) * 8], 16, 0, 0);

        // ---- h1 chunk via MFMA from register B-frags ----
        short8 a1 = *(const short8*)&w1l[(cc * 32 + mi * 16 + l15) * 32 + kg * 8];
        #pragma unroll
        for (int k = 0; k < 7; ++k) {
            int nj = njb + k * 8;
            if (nj <= 48) {
                int q = nj * 16 + l15;
                f32x4 hacc = (f32x4){0.f, 0.f, 0.f, 0.f};
                hacc = __builtin_amdgcn_mfma_f32_16x16x32_bf16(a1, bfrag[k], hacc, 0, 0, 0);
                int r = q / 130, c = q - r * 130;
                int gy = y0 - 1 + r;
                bool zero = (q >= 780) || ((unsigned)gy >= 128u) || (c == 0) || (c == 129);
                short4v hv;
                #pragma unroll
                for (int rr = 0; rr < 4; ++rr) {
                    int cig = cc * 32 + mi * 16 + kg * 4 + rr;
                    float h = fmaxf(fmaf(s1sh[cig], hacc[rr], t1sh[cig]), 0.f);
                    hv[rr] = zero ? (short)0 : (short)bfbits(h);
                }
                if (q < 780)
                    *(short4v*)&inT[(r * 130 + c) * 40 + mi * 16 + kg * 4] = hv;
            }
        }
        __syncthreads();   // inT written, wc DMA drained

        // ---- conv2: 9 taps x 16 MFMA per wave ----
        #pragma unroll
        for (int kk = 0; kk < 9; ++kk) {
            const int ky = kk / 3, kx = kk % 3;
            short8 af[4], bfv[4];
            #pragma unroll
            for (int fm = 0; fm < 4; ++fm)
                af[fm] = *(const short8*)&wc[((kk * 4 + kg) * 128 + wm * 64 + fm * 16 + l15) * 8];
            #pragma unroll
            for (int fn = 0; fn < 4; ++fn) {
                int n = wn * 64 + fn * 16 + l15;
                int r = (n >> 7) + ky, c2 = (n & 127) + kx;
                bfv[fn] = *(const short8*)&inT[(r * 130 + c2) * 40 + kg * 8];
            }
            #pragma unroll
            for (int fm = 0; fm < 4; ++fm)
                #pragma unroll
                for (int fn = 0; fn < 4; ++fn)
                    acc[fm][fn] = __builtin_amdgcn_mfma_f32_16x16x32_bf16(af[fm], bfv[fn], acc[fm][fn], 0, 0, 0);
        }
        __syncthreads();   // wc/inT reads done before next cc rewrites
    }

    // ---- epilogue: stats + coalesced y2 via LDS repack (pt = wc region) ----
    unsigned short* pt = wc;
    #pragma unroll
    for (int fm = 0; fm < 4; ++fm) {
        #pragma unroll
        for (int r = 0; r < 4; ++r) {
            const int col = fm * 16 + kg * 4 + r;
            const int co  = wm * 64 + col;
            const float bb = b2[co];
            float ls = 0.f, lq = 0.f;
            #pragma unroll
            for (int fn = 0; fn < 4; ++fn) {
                float v = acc[fm][fn][r] + bb;
                ls += v; lq += v * v;
            }
            #pragma unroll
            for (int m = 1; m < 16; m <<= 1) {
                ls += __shfl_xor(ls, m, 64);
                lq += __shfl_xor(lq, m, 64);
            }
            if (l15 == 0) { atomicAdd(&redS[co], ls); atomicAdd(&redQ[co], lq); }
        }
    }
    if (wm == 0) {
        #pragma unroll
        for (int fm = 0; fm < 4; ++fm)
            #pragma unroll
            for (int r = 0; r < 4; ++r) {
                const int col = fm * 16 + kg * 4 + r;
                const float bb = b2[col];
                const int xr = ((col >> 2) & 3) << 4;
                #pragma unroll
                for (int fn = 0; fn < 4; ++fn) {
                    int n = wn * 64 + fn * 16 + l15;
                    pt[col * 512 + (n ^ xr)] = bfbits(acc[fm][fn][r] + bb);
                }
            }
    }
    __syncthreads();
    if (tid < 128) { atomicAdd(&sum2[tid], redS[tid]); atomicAdd(&sq2[tid], redQ[tid]); }
    {
        unsigned short* y2u = (unsigned short*)y2;
        int co_l = tid >> 4, sub = tid & 15;
        int xr = ((co_l >> 2) & 3) << 4;
        size_t base = (((size_t)b * C1_ + co_l) * H_ + y0) * (size_t)W_ + sub * 8;
        #pragma unroll
        for (int j = 0; j < 4; ++j) {
            int p = j * 128 + sub * 8;
            *(short8*)&y2u[base + (size_t)j * W_] = *(short8*)&pt[co_l * 512 + (p ^ xr)];
        }
    }
    __syncthreads();
    if (wm == 1) {
        #pragma unroll
        for (int fm = 0; fm < 4; ++fm)
            #pragma unroll
            for (int r = 0; r < 4; ++r) {
                const int col = fm * 16 + kg * 4 + r;
                const float bb = b2[64 + col];
                const int xr = ((col >> 2) & 3) << 4;
                #pragma unroll
                for (int fn = 0; fn < 4; ++fn) {
                    int n = wn * 64 + fn * 16 + l15;
                    pt[col * 512 + (n ^ xr)] = bfbits(acc[fm][fn][r] + bb);
                }
            }
    }
    __syncthreads();
    {
        unsigned short* y2u = (unsigned short*)y2;
        int co_l = tid >> 4, sub = tid & 15;
        int xr = ((co_l >> 2) & 3) << 4;
        size_t base = (((size_t)b * C1_ + 64 + co_l) * H_ + y0) * (size_t)W_ + sub * 8;
        #pragma unroll
        for (int j = 0; j < 4; ++j) {
            int p = j * 128 + sub * 8;
            *(short8*)&y2u[base + (size_t)j * W_] = *(short8*)&pt[co_l * 512 + (p ^ xr)];
        }
    }
}

// ---------------- lateral path: maxpool2 + conv3x3(2->2) pad1 ----------------
__global__ __launch_bounds__(256) void poolconv_k(const float* __restrict__ out5,
                                                  const float* __restrict__ wl,
                                                  const float* __restrict__ bl,
                                                  float* __restrict__ ds) {
    int idx = blockIdx.x * 256 + threadIdx.x;
    int j = idx & 63;
    int i = (idx >> 6) & 63;
    int c = (idx >> 12) & 1;
    int b = idx >> 13;
    float acc = bl[c];
    #pragma unroll
    for (int ci = 0; ci < 2; ++ci) {
        const float* in = out5 + ((size_t)b * 5 + ci) * HW_;
        #pragma unroll
        for (int ky = 0; ky < 3; ++ky) {
            int ii = i + ky - 1;
            if (ii < 0 || ii > 63) continue;
            #pragma unroll
            for (int kx = 0; kx < 3; ++kx) {
                int jj = j + kx - 1;
                if (jj < 0 || jj > 63) continue;
                const float* p = in + (2 * ii) * W_ + 2 * jj;
                float pooled = fmaxf(fmaxf(p[0], p[1]), fmaxf(p[W_], p[W_ + 1]));
                acc += pooled * wl[(c * 2 + ci) * 9 + ky * 3 + kx];
            }
        }
    }
    ds[idx] = acc;
}

// ---------------- final: conv1x1(BN2+ReLU) + upsample + softmax + sigmoids, 4 px/thr ----
__global__ __launch_bounds__(256) void final_k(const float* __restrict__ out5,
                                               const __hip_bfloat16* __restrict__ y2,
                                               const float* __restrict__ s2,
                                               const float* __restrict__ t2,
                                               const float* __restrict__ w3,
                                               const float* __restrict__ b3,
                                               const float* __restrict__ dsb,
                                               float* __restrict__ out) {
    __shared__ float w3s[256], s2s[128], t2s[128];
    int tid = threadIdx.x;
    w3s[tid] = w3[tid];
    if (tid < 128) { s2s[tid] = s2[tid]; t2s[tid] = t2[tid]; }
    __syncthreads();
    int gid = blockIdx.x * 256 + tid;       // 131072 threads, 4 px each
    int b = gid >> 12;
    int rem = gid & 4095;
    int y = rem >> 5;
    int x0 = (rem & 31) * 4;
    int p = y * W_ + x0;

    const unsigned short* yp = (const unsigned short*)y2 + (size_t)b * C1_ * HW_ + p;
    float jm0[4], jm1[4];
    #pragma unroll
    for (int i = 0; i < 4; ++i) { jm0[i] = b3[0]; jm1[i] = b3[1]; }
    for (int ci = 0; ci < 128; ++ci) {
        short4v v = *(const short4v*)(yp + (size_t)ci * HW_);
        float sc = s2s[ci], tc = t2s[ci];
        float w0 = w3s[ci], w1c = w3s[128 + ci];
        #pragma unroll
        for (int i = 0; i < 4; ++i) {
            float h = fmaxf(fmaf(sc, bf2f((unsigned short)v[i]), tc), 0.f);
            jm0[i] = fmaf(h, w0, jm0[i]);
            jm1[i] = fmaf(h, w1c, jm1[i]);
        }
    }

    const float fo = (float)(63.0 / 127.0);
    float sy = (float)y * fo;
    int ly = (int)floorf(sy); ly = ly < 0 ? 0 : (ly > 62 ? 62 : ly);
    float wy = sy - (float)ly;
    const float* dbase = dsb + ((size_t)b * 2) * 4096;
    f32x4 sig;
    #pragma unroll
    for (int i = 0; i < 4; ++i) {
        int x = x0 + i;
        float sx = (float)x * fo;
        int lx = (int)floorf(sx); lx = lx < 0 ? 0 : (lx > 62 ? 62 : lx);
        float wx = sx - (float)lx;
        float up[2];
        #pragma unroll
        for (int c = 0; c < 2; ++c) {
            const float* d = dbase + c * 4096;
            float d00 = d[ly * 64 + lx],       d01 = d[ly * 64 + lx + 1];
            float d10 = d[(ly + 1) * 64 + lx], d11 = d[(ly + 1) * 64 + lx + 1];
            up[c] = (1.f - wy) * ((1.f - wx) * d00 + wx * d01) + wy * ((1.f - wx) * d10 + wx * d11);
        }
        float dlt = (jm1[i] + up[1]) - (jm0[i] + up[0]);
        sig[i] = 1.f / (1.f + expf(-dlt));
    }
    *(f32x4*)&out[(size_t)b * HW_ + p] = sig;

    {
        f32x4 lm = *(const f32x4*)&out5[((size_t)b * 5 + 2) * HW_ + p];
        f32x4 r;
        #pragma unroll
        for (int i = 0; i < 4; ++i) r[i] = 1.f / (1.f + expf(-lm[i]));
        *(f32x4*)&out[524288 + (size_t)b * HW_ + p] = r;
    }
    {
        f32x4 o3 = *(const f32x4*)&out5[((size_t)b * 5 + 3) * HW_ + p];
        f32x4 o4 = *(const f32x4*)&out5[((size_t)b * 5 + 4) * HW_ + p];
        f32x4 r3, r4;
        #pragma unroll
        for (int i = 0; i < 4; ++i) {
            r3[i] = 1.f / (1.f + expf(-o3[i])) - 0.5f;
            r4[i] = 1.f / (1.f + expf(-o4[i])) - 0.5f;
        }
        *(f32x4*)&out[1048576 + ((size_t)b * 2 + 0) * HW_ + p] = r3;
        *(f32x4*)&out[1048576 + ((size_t)b * 2 + 1) * HW_ + p] = r4;
    }
}

extern "C" void kernel_launch(void* const* d_in, const int* in_sizes, int n_in,
                              void* d_out, int out_size, void* d_ws, size_t ws_size,
                              hipStream_t stream) {
    const float* out5 = (const float*)d_in[0];
    const float* jmap = (const float*)d_in[1];
    const float* w1   = (const float*)d_in[2];
    const float* b1   = (const float*)d_in[3];
    const float* g1   = (const float*)d_in[4];
    const float* be1  = (const float*)d_in[5];
    const float* w2   = (const float*)d_in[6];
    const float* b2   = (const float*)d_in[7];
    const float* g2   = (const float*)d_in[8];
    const float* be2  = (const float*)d_in[9];
    const float* w3   = (const float*)d_in[10];
    const float* b3   = (const float*)d_in[11];
    const float* wl   = (const float*)d_in[12];
    const float* bl   = (const float*)d_in[13];
    const float* ga   = (const float*)d_in[14];
    const float* gb   = (const float*)d_in[15];
    float* out = (float*)d_out;

    // ws layout (~135.3 MB):
    //   [0, 134217728)           y2 bf16
    //   [134217728, +294912)     w2t2 } overlapped later by dsb (disjoint lifetimes)
    //   [134512640, +8192)       w1t  }
    //   [134217728, +1048576)    dsb (poolconv out; written after conv2 done)
    //   [135266304, +4096)       stats
    char* ws = (char*)d_ws;
    __hip_bfloat16* y2 = (__hip_bfloat16*)ws;
    unsigned short* w2t2 = (unsigned short*)(ws + 134217728);
    unsigned short* w1t  = (unsigned short*)(ws + 134512640);
    float* dsb = (float*)(ws + 134217728);
    float* st  = (float*)(ws + 135266304);
    float* sum1 = st;        float* sq1 = st + 128;
    float* sum2 = st + 256;  float* sq2 = st + 384;
    float* s1 = st + 512;    float* t1 = st + 640;
    float* s2 = st + 768;    float* t2 = st + 896;

    float* gtmp = out + 2097152;   // gauss target region of d_out

    prep_all<<<594, 256, 0, stream>>>(w2, w1, w2t2, w1t, st);
    gauss_k<<<32, 256, 0, stream>>>(jmap, gtmp, ga, gb);
    conv1stats_k<<<dim3(16, 32), 256, 0, stream>>>(out5, w1, b1, sum1, sq1);
    bnp_k<<<1, 128, 0, stream>>>(sum1, sq1, g1, be1, s1, t1);
    conv2_mfma<<<1024, 1024, 0, stream>>>(out5, b1, s1, t1, w2t2, w1t, b2, y2, sum2, sq2);
    bnp_k<<<1, 128, 0, stream>>>(sum2, sq2, g2, be2, s2, t2);
    poolconv_k<<<1024, 256, 0, stream>>>(out5, wl, bl, dsb);
    final_k<<<512, 256, 0, stream>>>(out5, y2, s2, t2, w3, b3, dsb, out);
}

// Round 10
// 366.307 us; speedup vs baseline: 1.8090x; 1.5840x over previous
//
#include <hip/hip_runtime.h>
#include <hip/hip_bf16.h>

#define B_   32
#define H_   128
#define W_   128
#define HW_  16384
#define C1_  128

typedef __attribute__((ext_vector_type(8))) short short8;
typedef __attribute__((ext_vector_type(4))) short short4v;
typedef __attribute__((ext_vector_type(4))) float f32x4;

static __device__ __forceinline__ unsigned short bfbits(float f) {
    __hip_bfloat16 h = __float2bfloat16(f);
    return *reinterpret_cast<unsigned short*>(&h);
}
static __device__ __forceinline__ float bf2f(unsigned int u) {
    union { unsigned int ui; float f; } cv; cv.ui = u << 16; return cv.f;
}

// ---- merged prep: w2t2 (r6 layout), w1t, zero stats ----
__global__ __launch_bounds__(256) void prep_all(const float* __restrict__ w2,
                                                const float* __restrict__ w1,
                                                unsigned short* __restrict__ w2t2,
                                                unsigned short* __restrict__ w1t,
                                                float* __restrict__ st) {
    int idx = blockIdx.x * 256 + threadIdx.x;
    if (idx < 147456) {
        int e  = idx & 7;
        int co = (idx >> 3) & 127;
        int kg = (idx >> 10) & 3;
        int t  = idx >> 12;          // 0..35
        int kk = t % 9, cc = t / 9;
        int ci = cc * 32 + kg * 8 + e;
        w2t2[idx] = bfbits(w2[((size_t)co * 128 + ci) * 9 + kk]);
    } else if (idx < 151552) {
        int i2 = idx - 147456;
        int k = i2 & 31, ci = i2 >> 5;
        w1t[i2] = (k < 18) ? bfbits(w1[ci * 18 + k]) : (unsigned short)0;
    } else if (idx < 152064) {
        st[idx - 151552] = 0.f;
    }
}

// ---------------- gaussian splat: vertical pass (±16 window; tail < 3e-14) ----------------
__global__ __launch_bounds__(256) void gauss_v(const float* __restrict__ jmap,
                                               float* __restrict__ gtmp,
                                               const float* __restrict__ ga,
                                               const float* __restrict__ gb) {
    __shared__ float k1[255];
    float a = ga[0] / (gb[0] * gb[0]);
    for (int i = threadIdx.x; i < 255; i += 256) {
        float d = (float)(i - 127);
        k1[i] = expf(a * d * d);
    }
    __syncthreads();
    int b = blockIdx.y;
    int y = blockIdx.x * 2 + (threadIdx.x >> 7);
    int x = threadIdx.x & 127;
    const float* m = jmap + (size_t)b * HW_;
    int lo = y - 16; if (lo < 0) lo = 0;
    int hi = y + 16; if (hi > 127) hi = 127;
    float s = 0.f;
    for (int yy = lo; yy <= hi; ++yy) {
        float mv = m[yy * W_ + x];
        s += (mv == 1.0f) ? k1[yy - y + 127] : 0.f;
    }
    gtmp[(size_t)b * HW_ + y * W_ + x] = s;
}

// ---------------- gaussian splat: horizontal pass + finalize (in-place) ----------------
__global__ __launch_bounds__(256) void gauss_h(const float* __restrict__ jmap,
                                               float* __restrict__ gtmp,
                                               const float* __restrict__ ga,
                                               const float* __restrict__ gb) {
    __shared__ float k1[255];
    __shared__ float row[256];
    float a = ga[0] / (gb[0] * gb[0]);
    for (int i = threadIdx.x; i < 255; i += 256) {
        float d = (float)(i - 127);
        k1[i] = expf(a * d * d);
    }
    int b = blockIdx.y;
    int y0 = blockIdx.x * 2;
    int tid = threadIdx.x;
    row[tid] = gtmp[(size_t)b * HW_ + (y0 + (tid >> 7)) * W_ + (tid & 127)];
    __syncthreads();
    int y = y0 + (tid >> 7);
    int x = tid & 127;
    int base = (tid >> 7) * 128;
    int lo = x - 16; if (lo < 0) lo = 0;
    int hi = x + 16; if (hi > 127) hi = 127;
    float s = 0.f;
    for (int xx = lo; xx <= hi; ++xx)
        s += k1[xx - x + 127] * row[base + xx];
    float g = jmap[(size_t)b * HW_ + y * W_ + x] + s;
    g = (g <= 0.05f) ? 0.f : fminf(g, 1.0f);
    gtmp[(size_t)b * HW_ + y * W_ + x] = g;
}

// ---------------- conv1 stats only (exact f32) ----------------
__global__ __launch_bounds__(256) void conv1stats_k(const float* __restrict__ out5,
                                                    const float* __restrict__ w1,
                                                    const float* __restrict__ b1,
                                                    float* __restrict__ sum1,
                                                    float* __restrict__ sq1) {
    int cg = blockIdx.x;
    int b  = blockIdx.y;
    int tid = threadIdx.x;
    __shared__ float wsh[8][18];
    __shared__ float bsh[8];
    __shared__ float red[256];
    for (int i = tid; i < 144; i += 256) wsh[i / 18][i % 18] = w1[cg * 8 * 18 + i];
    if (tid < 8) bsh[tid] = b1[cg * 8 + tid];
    __syncthreads();
    float ls[8], lq[8];
    #pragma unroll
    for (int i = 0; i < 8; ++i) { ls[i] = 0.f; lq[i] = 0.f; }
    const float* in0 = out5 + (size_t)b * 5 * HW_;
    const float* in1 = in0 + HW_;
    for (int pos = tid; pos < HW_; pos += 256) {
        int y = pos >> 7, x = pos & 127;
        float v0[9], v1[9];
        #pragma unroll
        for (int ky = 0; ky < 3; ++ky)
            #pragma unroll
            for (int kx = 0; kx < 3; ++kx) {
                int yy = y + ky - 1, xx = x + kx - 1;
                bool ok = ((unsigned)yy < 128u) && ((unsigned)xx < 128u);
                v0[ky * 3 + kx] = ok ? in0[yy * W_ + xx] : 0.f;
                v1[ky * 3 + kx] = ok ? in1[yy * W_ + xx] : 0.f;
            }
        #pragma unroll
        for (int i = 0; i < 8; ++i) {
            float a = bsh[i];
            #pragma unroll
            for (int k = 0; k < 9; ++k) a += v0[k] * wsh[i][k] + v1[k] * wsh[i][9 + k];
            ls[i] += a; lq[i] += a * a;
        }
    }
    for (int i = 0; i < 8; ++i) {
        red[tid] = ls[i]; __syncthreads();
        for (int s = 128; s > 0; s >>= 1) { if (tid < s) red[tid] += red[tid + s]; __syncthreads(); }
        if (tid == 0) atomicAdd(&sum1[cg * 8 + i], red[0]);
        __syncthreads();
        red[tid] = lq[i]; __syncthreads();
        for (int s = 128; s > 0; s >>= 1) { if (tid < s) red[tid] += red[tid + s]; __syncthreads(); }
        if (tid == 0) atomicAdd(&sq1[cg * 8 + i], red[0]);
        __syncthreads();
    }
}

// ---------------- conv2 via MFMA: GOLDEN r6 version + inline BN1 params ----------------
// 1024-thr block, co128 x pos512 (4 rows). Per cc: single 9-tap DMA burst + h1 phase
// (register B-frags) + 1 barrier + 9-tap MFMA + 1 barrier.
__global__ __launch_bounds__(1024) void conv2_mfma(
    const float* __restrict__ out5,
    const float* __restrict__ b1,
    const float* __restrict__ g1,
    const float* __restrict__ be1,
    const float* __restrict__ sum1,
    const float* __restrict__ sq1,
    const unsigned short* __restrict__ w2t2,
    const unsigned short* __restrict__ w1t,
    const float* __restrict__ b2,
    __hip_bfloat16* __restrict__ y2,
    float* __restrict__ sum2,
    float* __restrict__ sq2)
{
    __shared__ unsigned short inT[31200];   // h1: [r*130+c][40] (6 rows), 62400 B
    __shared__ unsigned short wc[36864];    // all 9 taps of one cc, 73728 B; reused as pt
    __shared__ unsigned short w1l[4096];    // conv1 weights [ci][32], 8192 B
    __shared__ float s1sh[128], t1sh[128], redS[128], redQ[128];

    const int tid = threadIdx.x;
    const int b  = blockIdx.x >> 5;
    const int y0 = (blockIdx.x & 31) * 4;
    const int lane = tid & 63, w = tid >> 6;   // w 0..15
    const int wm = w & 1, wn = w >> 1;         // co half / pos 64-group
    const int l15 = lane & 15, kg = lane >> 4;

    if (tid < 128) {
        redS[tid] = 0.f; redQ[tid] = 0.f;
        const float N = (float)(B_ * HW_);
        float m = sum1[tid] / N;
        float v = sq1[tid] / N - m * m;
        float sc = g1[tid] / sqrtf(v + 1e-5f);
        s1sh[tid] = sc;
        t1sh[tid] = fmaf(sc, b1[tid] - m, be1[tid]);   // fold conv1 bias into BN shift
    }
    if (tid < 512) *(short8*)&w1l[tid * 8] = *(const short8*)&w1t[tid * 8];

    // ---- prebuild h1 im2col B-fragments in registers (once) ----
    const float* in0 = out5 + (size_t)b * 5 * HW_;
    const float* in1 = in0 + HW_;
    const int mi  = wm;        // wave's conv1 ci-half
    const int njb = w >> 1;    // base position-tile
    short8 bfrag[7];
    #pragma unroll
    for (int k = 0; k < 7; ++k) {
        short8 f = (short8){0,0,0,0,0,0,0,0};
        int nj = njb + k * 8;
        int q  = nj * 16 + l15;
        if (nj <= 48 && q < 780) {
            int r = q / 130, c = q - r * 130;
            int gy = y0 - 1 + r, gx = c - 1;
            #pragma unroll
            for (int kk = 0; kk < 8; ++kk) {
                int kidx = kg * 8 + kk;
                unsigned short v = 0;
                if (kidx < 18) {
                    int ch = (kidx >= 9) ? 1 : 0;
                    int km = kidx - ch * 9;
                    int ky = km / 3, kx = km - ky * 3;
                    int yy = gy + ky - 1, xx = gx + kx - 1;
                    if ((unsigned)yy < 128u && (unsigned)xx < 128u)
                        v = bfbits((ch ? in1 : in0)[yy * W_ + xx]);
                }
                f[kk] = (short)v;
            }
        }
        bfrag[k] = f;
    }
    __syncthreads();   // w1l / s1sh / red zero visible

    f32x4 acc[4][4];
    #pragma unroll
    for (int fm = 0; fm < 4; ++fm)
        #pragma unroll
        for (int fn = 0; fn < 4; ++fn) acc[fm][fn] = (f32x4){0.f, 0.f, 0.f, 0.f};

    for (int cc = 0; cc < 4; ++cc) {
        // async stage all 9 taps' weights for this cc into wc (drained by next barrier)
        const unsigned short* wsrc = w2t2 + cc * 36864;
        #pragma unroll
        for (int u = 0; u < 4; ++u)
            __builtin_amdgcn_global_load_lds(
                (const unsigned int*)(wsrc + (u * 1024 + tid) * 8),
                (unsigned int*)&wc[(u * 1024 + tid) * 8], 16, 0, 0);
        if (tid < 512)
            __builtin_amdgcn_global_load_lds(
                (const unsigned int*)(wsrc + (4096 + tid) * 8),
                (unsigned int*)&wc[(4096 + tid) * 8], 16, 0, 0);

        // ---- h1 chunk via MFMA from register B-frags ----
        short8 a1 = *(const short8*)&w1l[(cc * 32 + mi * 16 + l15) * 32 + kg * 8];
        #pragma unroll
        for (int k = 0; k < 7; ++k) {
            int nj = njb + k * 8;
            if (nj <= 48) {
                int q = nj * 16 + l15;
                f32x4 hacc = (f32x4){0.f, 0.f, 0.f, 0.f};
                hacc = __builtin_amdgcn_mfma_f32_16x16x32_bf16(a1, bfrag[k], hacc, 0, 0, 0);
                int r = q / 130, c = q - r * 130;
                int gy = y0 - 1 + r;
                bool zero = (q >= 780) || ((unsigned)gy >= 128u) || (c == 0) || (c == 129);
                short4v hv;
                #pragma unroll
                for (int rr = 0; rr < 4; ++rr) {
                    int cig = cc * 32 + mi * 16 + kg * 4 + rr;
                    float h = fmaxf(fmaf(s1sh[cig], hacc[rr], t1sh[cig]), 0.f);
                    hv[rr] = zero ? (short)0 : (short)bfbits(h);
                }
                if (q < 780)
                    *(short4v*)&inT[(r * 130 + c) * 40 + mi * 16 + kg * 4] = hv;
            }
        }
        __syncthreads();   // inT written, wc DMA drained

        // ---- conv2: 9 taps x 16 MFMA per wave ----
        #pragma unroll
        for (int kk = 0; kk < 9; ++kk) {
            const int ky = kk / 3, kx = kk % 3;
            short8 af[4], bfv[4];
            #pragma unroll
            for (int fm = 0; fm < 4; ++fm)
                af[fm] = *(const short8*)&wc[((kk * 4 + kg) * 128 + wm * 64 + fm * 16 + l15) * 8];
            #pragma unroll
            for (int fn = 0; fn < 4; ++fn) {
                int n = wn * 64 + fn * 16 + l15;
                int r = (n >> 7) + ky, c2 = (n & 127) + kx;
                bfv[fn] = *(const short8*)&inT[(r * 130 + c2) * 40 + kg * 8];
            }
            #pragma unroll
            for (int fm = 0; fm < 4; ++fm)
                #pragma unroll
                for (int fn = 0; fn < 4; ++fn)
                    acc[fm][fn] = __builtin_amdgcn_mfma_f32_16x16x32_bf16(af[fm], bfv[fn], acc[fm][fn], 0, 0, 0);
        }
        __syncthreads();   // wc/inT reads done before next cc rewrites
    }

    // ---- epilogue: stats + coalesced y2 via LDS repack (pt = wc region) ----
    unsigned short* pt = wc;
    #pragma unroll
    for (int fm = 0; fm < 4; ++fm) {
        #pragma unroll
        for (int r = 0; r < 4; ++r) {
            const int col = fm * 16 + kg * 4 + r;
            const int co  = wm * 64 + col;
            const float bb = b2[co];
            float ls = 0.f, lq = 0.f;
            #pragma unroll
            for (int fn = 0; fn < 4; ++fn) {
                float v = acc[fm][fn][r] + bb;
                ls += v; lq += v * v;
            }
            #pragma unroll
            for (int m = 1; m < 16; m <<= 1) {
                ls += __shfl_xor(ls, m, 64);
                lq += __shfl_xor(lq, m, 64);
            }
            if (l15 == 0) { atomicAdd(&redS[co], ls); atomicAdd(&redQ[co], lq); }
        }
    }
    if (wm == 0) {
        #pragma unroll
        for (int fm = 0; fm < 4; ++fm)
            #pragma unroll
            for (int r = 0; r < 4; ++r) {
                const int col = fm * 16 + kg * 4 + r;
                const float bb = b2[col];
                const int xr = ((col >> 2) & 3) << 4;
                #pragma unroll
                for (int fn = 0; fn < 4; ++fn) {
                    int n = wn * 64 + fn * 16 + l15;
                    pt[col * 512 + (n ^ xr)] = bfbits(acc[fm][fn][r] + bb);
                }
            }
    }
    __syncthreads();
    if (tid < 128) { atomicAdd(&sum2[tid], redS[tid]); atomicAdd(&sq2[tid], redQ[tid]); }
    {
        unsigned short* y2u = (unsigned short*)y2;
        int co_l = tid >> 4, sub = tid & 15;
        int xr = ((co_l >> 2) & 3) << 4;
        size_t base = (((size_t)b * C1_ + co_l) * H_ + y0) * (size_t)W_ + sub * 8;
        #pragma unroll
        for (int j = 0; j < 4; ++j) {
            int p = j * 128 + sub * 8;
            *(short8*)&y2u[base + (size_t)j * W_] = *(short8*)&pt[co_l * 512 + (p ^ xr)];
        }
    }
    __syncthreads();
    if (wm == 1) {
        #pragma unroll
        for (int fm = 0; fm < 4; ++fm)
            #pragma unroll
            for (int r = 0; r < 4; ++r) {
                const int col = fm * 16 + kg * 4 + r;
                const float bb = b2[64 + col];
                const int xr = ((col >> 2) & 3) << 4;
                #pragma unroll
                for (int fn = 0; fn < 4; ++fn) {
                    int n = wn * 64 + fn * 16 + l15;
                    pt[col * 512 + (n ^ xr)] = bfbits(acc[fm][fn][r] + bb);
                }
            }
    }
    __syncthreads();
    {
        unsigned short* y2u = (unsigned short*)y2;
        int co_l = tid >> 4, sub = tid & 15;
        int xr = ((co_l >> 2) & 3) << 4;
        size_t base = (((size_t)b * C1_ + 64 + co_l) * H_ + y0) * (size_t)W_ + sub * 8;
        #pragma unroll
        for (int j = 0; j < 4; ++j) {
            int p = j * 128 + sub * 8;
            *(short8*)&y2u[base + (size_t)j * W_] = *(short8*)&pt[co_l * 512 + (p ^ xr)];
        }
    }
}

// ---------------- lateral path: maxpool2 + conv3x3(2->2) pad1 ----------------
__global__ __launch_bounds__(256) void poolconv_k(const float* __restrict__ out5,
                                                  const float* __restrict__ wl,
                                                  const float* __restrict__ bl,
                                                  float* __restrict__ ds) {
    int idx = blockIdx.x * 256 + threadIdx.x;
    int j = idx & 63;
    int i = (idx >> 6) & 63;
    int c = (idx >> 12) & 1;
    int b = idx >> 13;
    float acc = bl[c];
    #pragma unroll
    for (int ci = 0; ci < 2; ++ci) {
        const float* in = out5 + ((size_t)b * 5 + ci) * HW_;
        #pragma unroll
        for (int ky = 0; ky < 3; ++ky) {
            int ii = i + ky - 1;
            if (ii < 0 || ii > 63) continue;
            #pragma unroll
            for (int kx = 0; kx < 3; ++kx) {
                int jj = j + kx - 1;
                if (jj < 0 || jj > 63) continue;
                const float* p = in + (2 * ii) * W_ + 2 * jj;
                float pooled = fmaxf(fmaxf(p[0], p[1]), fmaxf(p[W_], p[W_ + 1]));
                acc += pooled * wl[(c * 2 + ci) * 9 + ky * 3 + kx];
            }
        }
    }
    ds[idx] = acc;
}

// ---------------- final: conv1x1(inline BN2+ReLU) + upsample + softmax + sigmoids, 4 px/thr ----
__global__ __launch_bounds__(256) void final_k(const float* __restrict__ out5,
                                               const __hip_bfloat16* __restrict__ y2,
                                               const float* __restrict__ g2,
                                               const float* __restrict__ be2,
                                               const float* __restrict__ sum2,
                                               const float* __restrict__ sq2,
                                               const float* __restrict__ w3,
                                               const float* __restrict__ b3,
                                               const float* __restrict__ dsb,
                                               float* __restrict__ out) {
    __shared__ float w3s[256], s2s[128], t2s[128];
    int tid = threadIdx.x;
    w3s[tid] = w3[tid];
    if (tid < 128) {
        const float N = (float)(B_ * HW_);
        float m = sum2[tid] / N;
        float v = sq2[tid] / N - m * m;
        float sc = g2[tid] / sqrtf(v + 1e-5f);
        s2s[tid] = sc;
        t2s[tid] = be2[tid] - sc * m;
    }
    __syncthreads();
    int gid = blockIdx.x * 256 + tid;       // 131072 threads, 4 px each
    int b = gid >> 12;
    int rem = gid & 4095;
    int y = rem >> 5;
    int x0 = (rem & 31) * 4;
    int p = y * W_ + x0;

    const unsigned short* yp = (const unsigned short*)y2 + (size_t)b * C1_ * HW_ + p;
    float jm0[4], jm1[4];
    #pragma unroll
    for (int i = 0; i < 4; ++i) { jm0[i] = b3[0]; jm1[i] = b3[1]; }
    for (int ci = 0; ci < 128; ++ci) {
        short4v v = *(const short4v*)(yp + (size_t)ci * HW_);
        float sc = s2s[ci], tc = t2s[ci];
        float w0 = w3s[ci], w1c = w3s[128 + ci];
        #pragma unroll
        for (int i = 0; i < 4; ++i) {
            float h = fmaxf(fmaf(sc, bf2f((unsigned short)v[i]), tc), 0.f);
            jm0[i] = fmaf(h, w0, jm0[i]);
            jm1[i] = fmaf(h, w1c, jm1[i]);
        }
    }

    const float fo = (float)(63.0 / 127.0);
    float sy = (float)y * fo;
    int ly = (int)floorf(sy); ly = ly < 0 ? 0 : (ly > 62 ? 62 : ly);
    float wy = sy - (float)ly;
    const float* dbase = dsb + ((size_t)b * 2) * 4096;
    f32x4 sig;
    #pragma unroll
    for (int i = 0; i < 4; ++i) {
        int x = x0 + i;
        float sx = (float)x * fo;
        int lx = (int)floorf(sx); lx = lx < 0 ? 0 : (lx > 62 ? 62 : lx);
        float wx = sx - (float)lx;
        float up[2];
        #pragma unroll
        for (int c = 0; c < 2; ++c) {
            const float* d = dbase + c * 4096;
            float d00 = d[ly * 64 + lx],       d01 = d[ly * 64 + lx + 1];
            float d10 = d[(ly + 1) * 64 + lx], d11 = d[(ly + 1) * 64 + lx + 1];
            up[c] = (1.f - wy) * ((1.f - wx) * d00 + wx * d01) + wy * ((1.f - wx) * d10 + wx * d11);
        }
        float dlt = (jm1[i] + up[1]) - (jm0[i] + up[0]);
        sig[i] = 1.f / (1.f + expf(-dlt));
    }
    *(f32x4*)&out[(size_t)b * HW_ + p] = sig;

    {
        f32x4 lm = *(const f32x4*)&out5[((size_t)b * 5 + 2) * HW_ + p];
        f32x4 r;
        #pragma unroll
        for (int i = 0; i < 4; ++i) r[i] = 1.f / (1.f + expf(-lm[i]));
        *(f32x4*)&out[524288 + (size_t)b * HW_ + p] = r;
    }
    {
        f32x4 o3 = *(const f32x4*)&out5[((size_t)b * 5 + 3) * HW_ + p];
        f32x4 o4 = *(const f32x4*)&out5[((size_t)b * 5 + 4) * HW_ + p];
        f32x4 r3, r4;
        #pragma unroll
        for (int i = 0; i < 4; ++i) {
            r3[i] = 1.f / (1.f + expf(-o3[i])) - 0.5f;
            r4[i] = 1.f / (1.f + expf(-o4[i])) - 0.5f;
        }
        *(f32x4*)&out[1048576 + ((size_t)b * 2 + 0) * HW_ + p] = r3;
        *(f32x4*)&out[1048576 + ((size_t)b * 2 + 1) * HW_ + p] = r4;
    }
}

extern "C" void kernel_launch(void* const* d_in, const int* in_sizes, int n_in,
                              void* d_out, int out_size, void* d_ws, size_t ws_size,
                              hipStream_t stream) {
    const float* out5 = (const float*)d_in[0];
    const float* jmap = (const float*)d_in[1];
    const float* w1   = (const float*)d_in[2];
    const float* b1   = (const float*)d_in[3];
    const float* g1   = (const float*)d_in[4];
    const float* be1  = (const float*)d_in[5];
    const float* w2   = (const float*)d_in[6];
    const float* b2   = (const float*)d_in[7];
    const float* g2   = (const float*)d_in[8];
    const float* be2  = (const float*)d_in[9];
    const float* w3   = (const float*)d_in[10];
    const float* b3   = (const float*)d_in[11];
    const float* wl   = (const float*)d_in[12];
    const float* bl   = (const float*)d_in[13];
    const float* ga   = (const float*)d_in[14];
    const float* gb   = (const float*)d_in[15];
    float* out = (float*)d_out;

    // ws layout (~135.3 MB):
    //   [0, 134217728)           y2 bf16
    //   [134217728, +294912)     w2t2 } overlapped later by dsb (disjoint lifetimes)
    //   [134512640, +8192)       w1t  }
    //   [134217728, +1048576)    dsb (poolconv out; written after conv2 done)
    //   [135266304, +4096)       stats
    char* ws = (char*)d_ws;
    __hip_bfloat16* y2 = (__hip_bfloat16*)ws;
    unsigned short* w2t2 = (unsigned short*)(ws + 134217728);
    unsigned short* w1t  = (unsigned short*)(ws + 134512640);
    float* dsb = (float*)(ws + 134217728);
    float* st  = (float*)(ws + 135266304);
    float* sum1 = st;        float* sq1 = st + 128;
    float* sum2 = st + 256;  float* sq2 = st + 384;

    float* gtmp = out + 2097152;   // gauss target region of d_out

    prep_all<<<594, 256, 0, stream>>>(w2, w1, w2t2, w1t, st);
    gauss_v<<<dim3(64, 32), 256, 0, stream>>>(jmap, gtmp, ga, gb);
    gauss_h<<<dim3(64, 32), 256, 0, stream>>>(jmap, gtmp, ga, gb);
    conv1stats_k<<<dim3(16, 32), 256, 0, stream>>>(out5, w1, b1, sum1, sq1);
    conv2_mfma<<<1024, 1024, 0, stream>>>(out5, b1, g1, be1, sum1, sq1, w2t2, w1t, b2, y2, sum2, sq2);
    poolconv_k<<<1024, 256, 0, stream>>>(out5, wl, bl, dsb);
    final_k<<<512, 256, 0, stream>>>(out5, y2, g2, be2, sum2, sq2, w3, b3, dsb, out);
}

// Round 11
// 348.322 us; speedup vs baseline: 1.9024x; 1.0516x over previous
//
#include <hip/hip_runtime.h>
#include <hip/hip_bf16.h>

#define B_   32
#define H_   128
#define W_   128
#define HW_  16384
#define C1_  128

typedef __attribute__((ext_vector_type(8))) short short8;
typedef __attribute__((ext_vector_type(4))) short short4v;
typedef __attribute__((ext_vector_type(4))) float f32x4;

static __device__ __forceinline__ unsigned short bfbits(float f) {
    __hip_bfloat16 h = __float2bfloat16(f);
    return *reinterpret_cast<unsigned short*>(&h);
}
static __device__ __forceinline__ float bf2f(unsigned int u) {
    union { unsigned int ui; float f; } cv; cv.ui = u << 16; return cv.f;
}

// ---- merged prep: w2t2 (r6 layout), w1t, zero stats ----
__global__ __launch_bounds__(256) void prep_all(const float* __restrict__ w2,
                                                const float* __restrict__ w1,
                                                unsigned short* __restrict__ w2t2,
                                                unsigned short* __restrict__ w1t,
                                                float* __restrict__ st) {
    int idx = blockIdx.x * 256 + threadIdx.x;
    if (idx < 147456) {
        int e  = idx & 7;
        int co = (idx >> 3) & 127;
        int kg = (idx >> 10) & 3;
        int t  = idx >> 12;          // 0..35
        int kk = t % 9, cc = t / 9;
        int ci = cc * 32 + kg * 8 + e;
        w2t2[idx] = bfbits(w2[((size_t)co * 128 + ci) * 9 + kk]);
    } else if (idx < 151552) {
        int i2 = idx - 147456;
        int k = i2 & 31, ci = i2 >> 5;
        w1t[i2] = (k < 18) ? bfbits(w1[ci * 18 + k]) : (unsigned short)0;
    } else if (idx < 152064) {
        st[idx - 151552] = 0.f;
    }
}

// ---------------- gaussian splat: vertical pass (±16 window; tail < 3e-14) ----------------
__global__ __launch_bounds__(256) void gauss_v(const float* __restrict__ jmap,
                                               float* __restrict__ gtmp,
                                               const float* __restrict__ ga,
                                               const float* __restrict__ gb) {
    __shared__ float k1[255];
    float a = ga[0] / (gb[0] * gb[0]);
    for (int i = threadIdx.x; i < 255; i += 256) {
        float d = (float)(i - 127);
        k1[i] = expf(a * d * d);
    }
    __syncthreads();
    int b = blockIdx.y;
    int y = blockIdx.x * 2 + (threadIdx.x >> 7);
    int x = threadIdx.x & 127;
    const float* m = jmap + (size_t)b * HW_;
    int lo = y - 16; if (lo < 0) lo = 0;
    int hi = y + 16; if (hi > 127) hi = 127;
    float s = 0.f;
    for (int yy = lo; yy <= hi; ++yy) {
        float mv = m[yy * W_ + x];
        s += (mv == 1.0f) ? k1[yy - y + 127] : 0.f;
    }
    gtmp[(size_t)b * HW_ + y * W_ + x] = s;
}

// ---------------- gaussian splat: horizontal pass + finalize (in-place) ----------------
__global__ __launch_bounds__(256) void gauss_h(const float* __restrict__ jmap,
                                               float* __restrict__ gtmp,
                                               const float* __restrict__ ga,
                                               const float* __restrict__ gb) {
    __shared__ float k1[255];
    __shared__ float row[256];
    float a = ga[0] / (gb[0] * gb[0]);
    for (int i = threadIdx.x; i < 255; i += 256) {
        float d = (float)(i - 127);
        k1[i] = expf(a * d * d);
    }
    int b = blockIdx.y;
    int y0 = blockIdx.x * 2;
    int tid = threadIdx.x;
    row[tid] = gtmp[(size_t)b * HW_ + (y0 + (tid >> 7)) * W_ + (tid & 127)];
    __syncthreads();
    int y = y0 + (tid >> 7);
    int x = tid & 127;
    int base = (tid >> 7) * 128;
    int lo = x - 16; if (lo < 0) lo = 0;
    int hi = x + 16; if (hi > 127) hi = 127;
    float s = 0.f;
    for (int xx = lo; xx <= hi; ++xx)
        s += k1[xx - x + 127] * row[base + xx];
    float g = jmap[(size_t)b * HW_ + y * W_ + x] + s;
    g = (g <= 0.05f) ? 0.f : fminf(g, 1.0f);
    gtmp[(size_t)b * HW_ + y * W_ + x] = g;
}

// ---------------- conv1 stats via MFMA (ports conv2's h1 pattern; h = conv1+b1) ----------
// 1024-thr block, grid 1024: 4 rows x 128 pos, all 128 ci. 64 tiles over 16 waves.
__global__ __launch_bounds__(1024) void conv1stats_mfma(
    const float* __restrict__ out5,
    const float* __restrict__ b1,
    const unsigned short* __restrict__ w1t,
    float* __restrict__ sum1,
    float* __restrict__ sq1)
{
    __shared__ unsigned short w1l[4096];
    __shared__ float b1sh[128], redS[128], redQ[128];
    const int tid = threadIdx.x;
    const int b  = blockIdx.x >> 5;
    const int y0 = (blockIdx.x & 31) * 4;
    const int lane = tid & 63, w = tid >> 6;   // 16 waves
    const int wm = w & 1;                      // ci half
    const int njb = w >> 1;                    // pos-tile base (0..7)
    const int l15 = lane & 15, kg = lane >> 4;

    if (tid < 128) { redS[tid] = 0.f; redQ[tid] = 0.f; b1sh[tid] = b1[tid]; }
    if (tid < 512) *(short8*)&w1l[tid * 8] = *(const short8*)&w1t[tid * 8];

    const float* in0 = out5 + (size_t)b * 5 * HW_;
    const float* in1 = in0 + HW_;
    short8 bfrag[4];
    #pragma unroll
    for (int k = 0; k < 4; ++k) {
        short8 f = (short8){0,0,0,0,0,0,0,0};
        int q = (njb + k * 8) * 16 + l15;      // 0..511
        int gy = y0 + (q >> 7), gx = q & 127;
        #pragma unroll
        for (int kk = 0; kk < 8; ++kk) {
            int kidx = kg * 8 + kk;
            unsigned short v = 0;
            if (kidx < 18) {
                int ch = (kidx >= 9) ? 1 : 0;
                int km = kidx - ch * 9;
                int ky = km / 3, kx = km - ky * 3;
                int yy = gy + ky - 1, xx = gx + kx - 1;
                if ((unsigned)yy < 128u && (unsigned)xx < 128u)
                    v = bfbits((ch ? in1 : in0)[yy * W_ + xx]);
            }
            f[kk] = (short)v;
        }
        bfrag[k] = f;
    }
    __syncthreads();

    #pragma unroll
    for (int cc = 0; cc < 4; ++cc) {
        short8 a1 = *(const short8*)&w1l[(cc * 32 + wm * 16 + l15) * 32 + kg * 8];
        float ls[4] = {0.f, 0.f, 0.f, 0.f}, lq[4] = {0.f, 0.f, 0.f, 0.f};
        #pragma unroll
        for (int k = 0; k < 4; ++k) {
            f32x4 hacc = (f32x4){0.f, 0.f, 0.f, 0.f};
            hacc = __builtin_amdgcn_mfma_f32_16x16x32_bf16(a1, bfrag[k], hacc, 0, 0, 0);
            #pragma unroll
            for (int rr = 0; rr < 4; ++rr) {
                float h = hacc[rr] + b1sh[cc * 32 + wm * 16 + kg * 4 + rr];
                ls[rr] += h; lq[rr] += h * h;
            }
        }
        #pragma unroll
        for (int rr = 0; rr < 4; ++rr) {
            #pragma unroll
            for (int m = 1; m < 16; m <<= 1) {
                ls[rr] += __shfl_xor(ls[rr], m, 64);
                lq[rr] += __shfl_xor(lq[rr], m, 64);
            }
            if (l15 == 0) {
                int ci = cc * 32 + wm * 16 + kg * 4 + rr;
                atomicAdd(&redS[ci], ls[rr]);
                atomicAdd(&redQ[ci], lq[rr]);
            }
        }
    }
    __syncthreads();
    if (tid < 128) { atomicAdd(&sum1[tid], redS[tid]); atomicAdd(&sq1[tid], redQ[tid]); }
}

// ---------------- conv2 via MFMA: GOLDEN r6 version + inline BN1 params ----------------
__global__ __launch_bounds__(1024) void conv2_mfma(
    const float* __restrict__ out5,
    const float* __restrict__ b1,
    const float* __restrict__ g1,
    const float* __restrict__ be1,
    const float* __restrict__ sum1,
    const float* __restrict__ sq1,
    const unsigned short* __restrict__ w2t2,
    const unsigned short* __restrict__ w1t,
    const float* __restrict__ b2,
    __hip_bfloat16* __restrict__ y2,
    float* __restrict__ sum2,
    float* __restrict__ sq2)
{
    __shared__ unsigned short inT[31200];
    __shared__ unsigned short wc[36864];
    __shared__ unsigned short w1l[4096];
    __shared__ float s1sh[128], t1sh[128], redS[128], redQ[128];

    const int tid = threadIdx.x;
    const int b  = blockIdx.x >> 5;
    const int y0 = (blockIdx.x & 31) * 4;
    const int lane = tid & 63, w = tid >> 6;
    const int wm = w & 1, wn = w >> 1;
    const int l15 = lane & 15, kg = lane >> 4;

    if (tid < 128) {
        redS[tid] = 0.f; redQ[tid] = 0.f;
        const float N = (float)(B_ * HW_);
        float m = sum1[tid] / N;
        float v = sq1[tid] / N - m * m;
        float sc = g1[tid] / sqrtf(v + 1e-5f);
        s1sh[tid] = sc;
        t1sh[tid] = fmaf(sc, b1[tid] - m, be1[tid]);
    }
    if (tid < 512) *(short8*)&w1l[tid * 8] = *(const short8*)&w1t[tid * 8];

    const float* in0 = out5 + (size_t)b * 5 * HW_;
    const float* in1 = in0 + HW_;
    const int mi  = wm;
    const int njb = w >> 1;
    short8 bfrag[7];
    #pragma unroll
    for (int k = 0; k < 7; ++k) {
        short8 f = (short8){0,0,0,0,0,0,0,0};
        int nj = njb + k * 8;
        int q  = nj * 16 + l15;
        if (nj <= 48 && q < 780) {
            int r = q / 130, c = q - r * 130;
            int gy = y0 - 1 + r, gx = c - 1;
            #pragma unroll
            for (int kk = 0; kk < 8; ++kk) {
                int kidx = kg * 8 + kk;
                unsigned short v = 0;
                if (kidx < 18) {
                    int ch = (kidx >= 9) ? 1 : 0;
                    int km = kidx - ch * 9;
                    int ky = km / 3, kx = km - ky * 3;
                    int yy = gy + ky - 1, xx = gx + kx - 1;
                    if ((unsigned)yy < 128u && (unsigned)xx < 128u)
                        v = bfbits((ch ? in1 : in0)[yy * W_ + xx]);
                }
                f[kk] = (short)v;
            }
        }
        bfrag[k] = f;
    }
    __syncthreads();

    f32x4 acc[4][4];
    #pragma unroll
    for (int fm = 0; fm < 4; ++fm)
        #pragma unroll
        for (int fn = 0; fn < 4; ++fn) acc[fm][fn] = (f32x4){0.f, 0.f, 0.f, 0.f};

    for (int cc = 0; cc < 4; ++cc) {
        const unsigned short* wsrc = w2t2 + cc * 36864;
        #pragma unroll
        for (int u = 0; u < 4; ++u)
            __builtin_amdgcn_global_load_lds(
                (const unsigned int*)(wsrc + (u * 1024 + tid) * 8),
                (unsigned int*)&wc[(u * 1024 + tid) * 8], 16, 0, 0);
        if (tid < 512)
            __builtin_amdgcn_global_load_lds(
                (const unsigned int*)(wsrc + (4096 + tid) * 8),
                (unsigned int*)&wc[(4096 + tid) * 8], 16, 0, 0);

        short8 a1 = *(const short8*)&w1l[(cc * 32 + mi * 16 + l15) * 32 + kg * 8];
        #pragma unroll
        for (int k = 0; k < 7; ++k) {
            int nj = njb + k * 8;
            if (nj <= 48) {
                int q = nj * 16 + l15;
                f32x4 hacc = (f32x4){0.f, 0.f, 0.f, 0.f};
                hacc = __builtin_amdgcn_mfma_f32_16x16x32_bf16(a1, bfrag[k], hacc, 0, 0, 0);
                int r = q / 130, c = q - r * 130;
                int gy = y0 - 1 + r;
                bool zero = (q >= 780) || ((unsigned)gy >= 128u) || (c == 0) || (c == 129);
                short4v hv;
                #pragma unroll
                for (int rr = 0; rr < 4; ++rr) {
                    int cig = cc * 32 + mi * 16 + kg * 4 + rr;
                    float h = fmaxf(fmaf(s1sh[cig], hacc[rr], t1sh[cig]), 0.f);
                    hv[rr] = zero ? (short)0 : (short)bfbits(h);
                }
                if (q < 780)
                    *(short4v*)&inT[(r * 130 + c) * 40 + mi * 16 + kg * 4] = hv;
            }
        }
        __syncthreads();

        #pragma unroll
        for (int kk = 0; kk < 9; ++kk) {
            const int ky = kk / 3, kx = kk % 3;
            short8 af[4], bfv[4];
            #pragma unroll
            for (int fm = 0; fm < 4; ++fm)
                af[fm] = *(const short8*)&wc[((kk * 4 + kg) * 128 + wm * 64 + fm * 16 + l15) * 8];
            #pragma unroll
            for (int fn = 0; fn < 4; ++fn) {
                int n = wn * 64 + fn * 16 + l15;
                int r = (n >> 7) + ky, c2 = (n & 127) + kx;
                bfv[fn] = *(const short8*)&inT[(r * 130 + c2) * 40 + kg * 8];
            }
            #pragma unroll
            for (int fm = 0; fm < 4; ++fm)
                #pragma unroll
                for (int fn = 0; fn < 4; ++fn)
                    acc[fm][fn] = __builtin_amdgcn_mfma_f32_16x16x32_bf16(af[fm], bfv[fn], acc[fm][fn], 0, 0, 0);
        }
        __syncthreads();
    }

    unsigned short* pt = wc;
    #pragma unroll
    for (int fm = 0; fm < 4; ++fm) {
        #pragma unroll
        for (int r = 0; r < 4; ++r) {
            const int col = fm * 16 + kg * 4 + r;
            const int co  = wm * 64 + col;
            const float bb = b2[co];
            float ls = 0.f, lq = 0.f;
            #pragma unroll
            for (int fn = 0; fn < 4; ++fn) {
                float v = acc[fm][fn][r] + bb;
                ls += v; lq += v * v;
            }
            #pragma unroll
            for (int m = 1; m < 16; m <<= 1) {
                ls += __shfl_xor(ls, m, 64);
                lq += __shfl_xor(lq, m, 64);
            }
            if (l15 == 0) { atomicAdd(&redS[co], ls); atomicAdd(&redQ[co], lq); }
        }
    }
    if (wm == 0) {
        #pragma unroll
        for (int fm = 0; fm < 4; ++fm)
            #pragma unroll
            for (int r = 0; r < 4; ++r) {
                const int col = fm * 16 + kg * 4 + r;
                const float bb = b2[col];
                const int xr = ((col >> 2) & 3) << 4;
                #pragma unroll
                for (int fn = 0; fn < 4; ++fn) {
                    int n = wn * 64 + fn * 16 + l15;
                    pt[col * 512 + (n ^ xr)] = bfbits(acc[fm][fn][r] + bb);
                }
            }
    }
    __syncthreads();
    if (tid < 128) { atomicAdd(&sum2[tid], redS[tid]); atomicAdd(&sq2[tid], redQ[tid]); }
    {
        unsigned short* y2u = (unsigned short*)y2;
        int co_l = tid >> 4, sub = tid & 15;
        int xr = ((co_l >> 2) & 3) << 4;
        size_t base = (((size_t)b * C1_ + co_l) * H_ + y0) * (size_t)W_ + sub * 8;
        #pragma unroll
        for (int j = 0; j < 4; ++j) {
            int p = j * 128 + sub * 8;
            *(short8*)&y2u[base + (size_t)j * W_] = *(short8*)&pt[co_l * 512 + (p ^ xr)];
        }
    }
    __syncthreads();
    if (wm == 1) {
        #pragma unroll
        for (int fm = 0; fm < 4; ++fm)
            #pragma unroll
            for (int r = 0; r < 4; ++r) {
                const int col = fm * 16 + kg * 4 + r;
                const float bb = b2[64 + col];
                const int xr = ((col >> 2) & 3) << 4;
                #pragma unroll
                for (int fn = 0; fn < 4; ++fn) {
                    int n = wn * 64 + fn * 16 + l15;
                    pt[col * 512 + (n ^ xr)] = bfbits(acc[fm][fn][r] + bb);
                }
            }
    }
    __syncthreads();
    {
        unsigned short* y2u = (unsigned short*)y2;
        int co_l = tid >> 4, sub = tid & 15;
        int xr = ((co_l >> 2) & 3) << 4;
        size_t base = (((size_t)b * C1_ + 64 + co_l) * H_ + y0) * (size_t)W_ + sub * 8;
        #pragma unroll
        for (int j = 0; j < 4; ++j) {
            int p = j * 128 + sub * 8;
            *(short8*)&y2u[base + (size_t)j * W_] = *(short8*)&pt[co_l * 512 + (p ^ xr)];
        }
    }
}

// ---------------- lateral path: maxpool2 + conv3x3(2->2) pad1 ----------------
__global__ __launch_bounds__(256) void poolconv_k(const float* __restrict__ out5,
                                                  const float* __restrict__ wl,
                                                  const float* __restrict__ bl,
                                                  float* __restrict__ ds) {
    int idx = blockIdx.x * 256 + threadIdx.x;
    int j = idx & 63;
    int i = (idx >> 6) & 63;
    int c = (idx >> 12) & 1;
    int b = idx >> 13;
    float acc = bl[c];
    #pragma unroll
    for (int ci = 0; ci < 2; ++ci) {
        const float* in = out5 + ((size_t)b * 5 + ci) * HW_;
        #pragma unroll
        for (int ky = 0; ky < 3; ++ky) {
            int ii = i + ky - 1;
            if (ii < 0 || ii > 63) continue;
            #pragma unroll
            for (int kx = 0; kx < 3; ++kx) {
                int jj = j + kx - 1;
                if (jj < 0 || jj > 63) continue;
                const float* p = in + (2 * ii) * W_ + 2 * jj;
                float pooled = fmaxf(fmaxf(p[0], p[1]), fmaxf(p[W_], p[W_ + 1]));
                acc += pooled * wl[(c * 2 + ci) * 9 + ky * 3 + kx];
            }
        }
    }
    ds[idx] = acc;
}

// ---------------- final: conv1x1(inline BN2+ReLU) + upsample + softmax + sigmoids, 4 px/thr ----
__global__ __launch_bounds__(256) void final_k(const float* __restrict__ out5,
                                               const __hip_bfloat16* __restrict__ y2,
                                               const float* __restrict__ g2,
                                               const float* __restrict__ be2,
                                               const float* __restrict__ sum2,
                                               const float* __restrict__ sq2,
                                               const float* __restrict__ w3,
                                               const float* __restrict__ b3,
                                               const float* __restrict__ dsb,
                                               float* __restrict__ out) {
    __shared__ float w3s[256], s2s[128], t2s[128];
    int tid = threadIdx.x;
    w3s[tid] = w3[tid];
    if (tid < 128) {
        const float N = (float)(B_ * HW_);
        float m = sum2[tid] / N;
        float v = sq2[tid] / N - m * m;
        float sc = g2[tid] / sqrtf(v + 1e-5f);
        s2s[tid] = sc;
        t2s[tid] = be2[tid] - sc * m;
    }
    __syncthreads();
    int gid = blockIdx.x * 256 + tid;       // 131072 threads, 4 px each
    int b = gid >> 12;
    int rem = gid & 4095;
    int y = rem >> 5;
    int x0 = (rem & 31) * 4;
    int p = y * W_ + x0;

    const unsigned short* yp = (const unsigned short*)y2 + (size_t)b * C1_ * HW_ + p;
    float jm0[4], jm1[4];
    #pragma unroll
    for (int i = 0; i < 4; ++i) { jm0[i] = b3[0]; jm1[i] = b3[1]; }
    for (int ci = 0; ci < 128; ++ci) {
        short4v v = *(const short4v*)(yp + (size_t)ci * HW_);
        float sc = s2s[ci], tc = t2s[ci];
        float w0 = w3s[ci], w1c = w3s[128 + ci];
        #pragma unroll
        for (int i = 0; i < 4; ++i) {
            float h = fmaxf(fmaf(sc, bf2f((unsigned short)v[i]), tc), 0.f);
            jm0[i] = fmaf(h, w0, jm0[i]);
            jm1[i] = fmaf(h, w1c, jm1[i]);
        }
    }

    const float fo = (float)(63.0 / 127.0);
    float sy = (float)y * fo;
    int ly = (int)floorf(sy); ly = ly < 0 ? 0 : (ly > 62 ? 62 : ly);
    float wy = sy - (float)ly;
    const float* dbase = dsb + ((size_t)b * 2) * 4096;
    f32x4 sig;
    #pragma unroll
    for (int i = 0; i < 4; ++i) {
        int x = x0 + i;
        float sx = (float)x * fo;
        int lx = (int)floorf(sx); lx = lx < 0 ? 0 : (lx > 62 ? 62 : lx);
        float wx = sx - (float)lx;
        float up[2];
        #pragma unroll
        for (int c = 0; c < 2; ++c) {
            const float* d = dbase + c * 4096;
            float d00 = d[ly * 64 + lx],       d01 = d[ly * 64 + lx + 1];
            float d10 = d[(ly + 1) * 64 + lx], d11 = d[(ly + 1) * 64 + lx + 1];
            up[c] = (1.f - wy) * ((1.f - wx) * d00 + wx * d01) + wy * ((1.f - wx) * d10 + wx * d11);
        }
        float dlt = (jm1[i] + up[1]) - (jm0[i] + up[0]);
        sig[i] = 1.f / (1.f + expf(-dlt));
    }
    *(f32x4*)&out[(size_t)b * HW_ + p] = sig;

    {
        f32x4 lm = *(const f32x4*)&out5[((size_t)b * 5 + 2) * HW_ + p];
        f32x4 r;
        #pragma unroll
        for (int i = 0; i < 4; ++i) r[i] = 1.f / (1.f + expf(-lm[i]));
        *(f32x4*)&out[524288 + (size_t)b * HW_ + p] = r;
    }
    {
        f32x4 o3 = *(const f32x4*)&out5[((size_t)b * 5 + 3) * HW_ + p];
        f32x4 o4 = *(const f32x4*)&out5[((size_t)b * 5 + 4) * HW_ + p];
        f32x4 r3, r4;
        #pragma unroll
        for (int i = 0; i < 4; ++i) {
            r3[i] = 1.f / (1.f + expf(-o3[i])) - 0.5f;
            r4[i] = 1.f / (1.f + expf(-o4[i])) - 0.5f;
        }
        *(f32x4*)&out[1048576 + ((size_t)b * 2 + 0) * HW_ + p] = r3;
        *(f32x4*)&out[1048576 + ((size_t)b * 2 + 1) * HW_ + p] = r4;
    }
}

extern "C" void kernel_launch(void* const* d_in, const int* in_sizes, int n_in,
                              void* d_out, int out_size, void* d_ws, size_t ws_size,
                              hipStream_t stream) {
    const float* out5 = (const float*)d_in[0];
    const float* jmap = (const float*)d_in[1];
    const float* w1   = (const float*)d_in[2];
    const float* b1   = (const float*)d_in[3];
    const float* g1   = (const float*)d_in[4];
    const float* be1  = (const float*)d_in[5];
    const float* w2   = (const float*)d_in[6];
    const float* b2   = (const float*)d_in[7];
    const float* g2   = (const float*)d_in[8];
    const float* be2  = (const float*)d_in[9];
    const float* w3   = (const float*)d_in[10];
    const float* b3   = (const float*)d_in[11];
    const float* wl   = (const float*)d_in[12];
    const float* bl   = (const float*)d_in[13];
    const float* ga   = (const float*)d_in[14];
    const float* gb   = (const float*)d_in[15];
    float* out = (float*)d_out;

    // ws layout (~135.3 MB):
    //   [0, 134217728)           y2 bf16
    //   [134217728, +294912)     w2t2 } overlapped later by dsb (disjoint lifetimes)
    //   [134512640, +8192)       w1t  }
    //   [134217728, +1048576)    dsb (poolconv out; written after conv2 done)
    //   [135266304, +4096)       stats
    char* ws = (char*)d_ws;
    __hip_bfloat16* y2 = (__hip_bfloat16*)ws;
    unsigned short* w2t2 = (unsigned short*)(ws + 134217728);
    unsigned short* w1t  = (unsigned short*)(ws + 134512640);
    float* dsb = (float*)(ws + 134217728);
    float* st  = (float*)(ws + 135266304);
    float* sum1 = st;        float* sq1 = st + 128;
    float* sum2 = st + 256;  float* sq2 = st + 384;

    float* gtmp = out + 2097152;   // gauss target region of d_out

    prep_all<<<594, 256, 0, stream>>>(w2, w1, w2t2, w1t, st);
    gauss_v<<<dim3(64, 32), 256, 0, stream>>>(jmap, gtmp, ga, gb);
    gauss_h<<<dim3(64, 32), 256, 0, stream>>>(jmap, gtmp, ga, gb);
    conv1stats_mfma<<<1024, 1024, 0, stream>>>(out5, b1, w1t, sum1, sq1);
    conv2_mfma<<<1024, 1024, 0, stream>>>(out5, b1, g1, be1, sum1, sq1, w2t2, w1t, b2, y2, sum2, sq2);
    poolconv_k<<<1024, 256, 0, stream>>>(out5, wl, bl, dsb);
    final_k<<<512, 256, 0, stream>>>(out5, y2, g2, be2, sum2, sq2, w3, b3, dsb, out);
}

// Round 12
// 343.868 us; speedup vs baseline: 1.9271x; 1.0130x over previous
//
#include <hip/hip_runtime.h>
#include <hip/hip_bf16.h>

#define B_   32
#define H_   128
#define W_   128
#define HW_  16384
#define C1_  128

typedef __attribute__((ext_vector_type(8))) short short8;
typedef __attribute__((ext_vector_type(4))) short short4v;
typedef __attribute__((ext_vector_type(4))) float f32x4;

static __device__ __forceinline__ unsigned short bfbits(float f) {
    __hip_bfloat16 h = __float2bfloat16(f);
    return *reinterpret_cast<unsigned short*>(&h);
}
static __device__ __forceinline__ float bf2f(unsigned int u) {
    union { unsigned int ui; float f; } cv; cv.ui = u << 16; return cv.f;
}

// ---- merged prep: w2t2 (r6 layout), w1t, zero stats ----
__global__ __launch_bounds__(256) void prep_all(const float* __restrict__ w2,
                                                const float* __restrict__ w1,
                                                unsigned short* __restrict__ w2t2,
                                                unsigned short* __restrict__ w1t,
                                                float* __restrict__ st) {
    int idx = blockIdx.x * 256 + threadIdx.x;
    if (idx < 147456) {
        int e  = idx & 7;
        int co = (idx >> 3) & 127;
        int kg = (idx >> 10) & 3;
        int t  = idx >> 12;          // 0..35
        int kk = t % 9, cc = t / 9;
        int ci = cc * 32 + kg * 8 + e;
        w2t2[idx] = bfbits(w2[((size_t)co * 128 + ci) * 9 + kk]);
    } else if (idx < 151552) {
        int i2 = idx - 147456;
        int k = i2 & 31, ci = i2 >> 5;
        w1t[i2] = (k < 18) ? bfbits(w1[ci * 18 + k]) : (unsigned short)0;
    } else if (idx < 152064) {
        st[idx - 151552] = 0.f;
    }
}

// ---------------- gaussian splat: v-pass + h-pass fused (±16 window; tail < 3e-14) --------
// h-pass at row y needs only v-results of row y -> 2-row block does v->LDS->h in one kernel.
__global__ __launch_bounds__(256) void gauss_m(const float* __restrict__ jmap,
                                               float* __restrict__ outg,
                                               const float* __restrict__ ga,
                                               const float* __restrict__ gb) {
    __shared__ float k1[33];
    __shared__ float vrow[2][128];
    int tid = threadIdx.x;
    float a = ga[0] / (gb[0] * gb[0]);
    if (tid < 33) { float d = (float)tid - 16.f; k1[tid] = expf(a * d * d); }
    __syncthreads();
    int b = blockIdx.y;
    int ly = tid >> 7;
    int y = blockIdx.x * 2 + ly;
    int x = tid & 127;
    const float* m = jmap + (size_t)b * HW_;
    int lo = y - 16; if (lo < 0) lo = 0;
    int hi = y + 16; if (hi > 127) hi = 127;
    float s = 0.f;
    for (int yy = lo; yy <= hi; ++yy) {
        float mv = m[yy * W_ + x];
        s += (mv == 1.0f) ? k1[yy - y + 16] : 0.f;
    }
    vrow[ly][x] = s;
    __syncthreads();
    int lo2 = x - 16; if (lo2 < 0) lo2 = 0;
    int hi2 = x + 16; if (hi2 > 127) hi2 = 127;
    float s2 = 0.f;
    for (int xx = lo2; xx <= hi2; ++xx)
        s2 += k1[xx - x + 16] * vrow[ly][xx];
    float g = m[y * W_ + x] + s2;
    g = (g <= 0.05f) ? 0.f : fminf(g, 1.0f);
    outg[(size_t)b * HW_ + y * W_ + x] = g;
}

// ---------------- conv1 stats via MFMA (h = conv1+b1) ----------------
__global__ __launch_bounds__(1024) void conv1stats_mfma(
    const float* __restrict__ out5,
    const float* __restrict__ b1,
    const unsigned short* __restrict__ w1t,
    float* __restrict__ sum1,
    float* __restrict__ sq1)
{
    __shared__ unsigned short w1l[4096];
    __shared__ float b1sh[128], redS[128], redQ[128];
    const int tid = threadIdx.x;
    const int b  = blockIdx.x >> 5;
    const int y0 = (blockIdx.x & 31) * 4;
    const int lane = tid & 63, w = tid >> 6;   // 16 waves
    const int wm = w & 1;                      // ci half
    const int njb = w >> 1;                    // pos-tile base (0..7)
    const int l15 = lane & 15, kg = lane >> 4;

    if (tid < 128) { redS[tid] = 0.f; redQ[tid] = 0.f; b1sh[tid] = b1[tid]; }
    if (tid < 512) *(short8*)&w1l[tid * 8] = *(const short8*)&w1t[tid * 8];

    const float* in0 = out5 + (size_t)b * 5 * HW_;
    const float* in1 = in0 + HW_;
    short8 bfrag[4];
    #pragma unroll
    for (int k = 0; k < 4; ++k) {
        short8 f = (short8){0,0,0,0,0,0,0,0};
        int q = (njb + k * 8) * 16 + l15;      // 0..511
        int gy = y0 + (q >> 7), gx = q & 127;
        #pragma unroll
        for (int kk = 0; kk < 8; ++kk) {
            int kidx = kg * 8 + kk;
            unsigned short v = 0;
            if (kidx < 18) {
                int ch = (kidx >= 9) ? 1 : 0;
                int km = kidx - ch * 9;
                int ky = km / 3, kx = km - ky * 3;
                int yy = gy + ky - 1, xx = gx + kx - 1;
                if ((unsigned)yy < 128u && (unsigned)xx < 128u)
                    v = bfbits((ch ? in1 : in0)[yy * W_ + xx]);
            }
            f[kk] = (short)v;
        }
        bfrag[k] = f;
    }
    __syncthreads();

    #pragma unroll
    for (int cc = 0; cc < 4; ++cc) {
        short8 a1 = *(const short8*)&w1l[(cc * 32 + wm * 16 + l15) * 32 + kg * 8];
        float ls[4] = {0.f, 0.f, 0.f, 0.f}, lq[4] = {0.f, 0.f, 0.f, 0.f};
        #pragma unroll
        for (int k = 0; k < 4; ++k) {
            f32x4 hacc = (f32x4){0.f, 0.f, 0.f, 0.f};
            hacc = __builtin_amdgcn_mfma_f32_16x16x32_bf16(a1, bfrag[k], hacc, 0, 0, 0);
            #pragma unroll
            for (int rr = 0; rr < 4; ++rr) {
                float h = hacc[rr] + b1sh[cc * 32 + wm * 16 + kg * 4 + rr];
                ls[rr] += h; lq[rr] += h * h;
            }
        }
        #pragma unroll
        for (int rr = 0; rr < 4; ++rr) {
            #pragma unroll
            for (int m = 1; m < 16; m <<= 1) {
                ls[rr] += __shfl_xor(ls[rr], m, 64);
                lq[rr] += __shfl_xor(lq[rr], m, 64);
            }
            if (l15 == 0) {
                int ci = cc * 32 + wm * 16 + kg * 4 + rr;
                atomicAdd(&redS[ci], ls[rr]);
                atomicAdd(&redQ[ci], lq[rr]);
            }
        }
    }
    __syncthreads();
    if (tid < 128) { atomicAdd(&sum1[tid], redS[tid]); atomicAdd(&sq1[tid], redQ[tid]); }
}

// ---------------- conv2 via MFMA: GOLDEN r6 version + inline BN1 params ----------------
__global__ __launch_bounds__(1024) void conv2_mfma(
    const float* __restrict__ out5,
    const float* __restrict__ b1,
    const float* __restrict__ g1,
    const float* __restrict__ be1,
    const float* __restrict__ sum1,
    const float* __restrict__ sq1,
    const unsigned short* __restrict__ w2t2,
    const unsigned short* __restrict__ w1t,
    const float* __restrict__ b2,
    __hip_bfloat16* __restrict__ y2,
    float* __restrict__ sum2,
    float* __restrict__ sq2)
{
    __shared__ unsigned short inT[31200];
    __shared__ unsigned short wc[36864];
    __shared__ unsigned short w1l[4096];
    __shared__ float s1sh[128], t1sh[128], redS[128], redQ[128];

    const int tid = threadIdx.x;
    const int b  = blockIdx.x >> 5;
    const int y0 = (blockIdx.x & 31) * 4;
    const int lane = tid & 63, w = tid >> 6;
    const int wm = w & 1, wn = w >> 1;
    const int l15 = lane & 15, kg = lane >> 4;

    if (tid < 128) {
        redS[tid] = 0.f; redQ[tid] = 0.f;
        const float N = (float)(B_ * HW_);
        float m = sum1[tid] / N;
        float v = sq1[tid] / N - m * m;
        float sc = g1[tid] / sqrtf(v + 1e-5f);
        s1sh[tid] = sc;
        t1sh[tid] = fmaf(sc, b1[tid] - m, be1[tid]);
    }
    if (tid < 512) *(short8*)&w1l[tid * 8] = *(const short8*)&w1t[tid * 8];

    const float* in0 = out5 + (size_t)b * 5 * HW_;
    const float* in1 = in0 + HW_;
    const int mi  = wm;
    const int njb = w >> 1;
    short8 bfrag[7];
    #pragma unroll
    for (int k = 0; k < 7; ++k) {
        short8 f = (short8){0,0,0,0,0,0,0,0};
        int nj = njb + k * 8;
        int q  = nj * 16 + l15;
        if (nj <= 48 && q < 780) {
            int r = q / 130, c = q - r * 130;
            int gy = y0 - 1 + r, gx = c - 1;
            #pragma unroll
            for (int kk = 0; kk < 8; ++kk) {
                int kidx = kg * 8 + kk;
                unsigned short v = 0;
                if (kidx < 18) {
                    int ch = (kidx >= 9) ? 1 : 0;
                    int km = kidx - ch * 9;
                    int ky = km / 3, kx = km - ky * 3;
                    int yy = gy + ky - 1, xx = gx + kx - 1;
                    if ((unsigned)yy < 128u && (unsigned)xx < 128u)
                        v = bfbits((ch ? in1 : in0)[yy * W_ + xx]);
                }
                f[kk] = (short)v;
            }
        }
        bfrag[k] = f;
    }
    __syncthreads();

    f32x4 acc[4][4];
    #pragma unroll
    for (int fm = 0; fm < 4; ++fm)
        #pragma unroll
        for (int fn = 0; fn < 4; ++fn) acc[fm][fn] = (f32x4){0.f, 0.f, 0.f, 0.f};

    for (int cc = 0; cc < 4; ++cc) {
        const unsigned short* wsrc = w2t2 + cc * 36864;
        #pragma unroll
        for (int u = 0; u < 4; ++u)
            __builtin_amdgcn_global_load_lds(
                (const unsigned int*)(wsrc + (u * 1024 + tid) * 8),
                (unsigned int*)&wc[(u * 1024 + tid) * 8], 16, 0, 0);
        if (tid < 512)
            __builtin_amdgcn_global_load_lds(
                (const unsigned int*)(wsrc + (4096 + tid) * 8),
                (unsigned int*)&wc[(4096 + tid) * 8], 16, 0, 0);

        short8 a1 = *(const short8*)&w1l[(cc * 32 + mi * 16 + l15) * 32 + kg * 8];
        #pragma unroll
        for (int k = 0; k < 7; ++k) {
            int nj = njb + k * 8;
            if (nj <= 48) {
                int q = nj * 16 + l15;
                f32x4 hacc = (f32x4){0.f, 0.f, 0.f, 0.f};
                hacc = __builtin_amdgcn_mfma_f32_16x16x32_bf16(a1, bfrag[k], hacc, 0, 0, 0);
                int r = q / 130, c = q - r * 130;
                int gy = y0 - 1 + r;
                bool zero = (q >= 780) || ((unsigned)gy >= 128u) || (c == 0) || (c == 129);
                short4v hv;
                #pragma unroll
                for (int rr = 0; rr < 4; ++rr) {
                    int cig = cc * 32 + mi * 16 + kg * 4 + rr;
                    float h = fmaxf(fmaf(s1sh[cig], hacc[rr], t1sh[cig]), 0.f);
                    hv[rr] = zero ? (short)0 : (short)bfbits(h);
                }
                if (q < 780)
                    *(short4v*)&inT[(r * 130 + c) * 40 + mi * 16 + kg * 4] = hv;
            }
        }
        __syncthreads();

        #pragma unroll
        for (int kk = 0; kk < 9; ++kk) {
            const int ky = kk / 3, kx = kk % 3;
            short8 af[4], bfv[4];
            #pragma unroll
            for (int fm = 0; fm < 4; ++fm)
                af[fm] = *(const short8*)&wc[((kk * 4 + kg) * 128 + wm * 64 + fm * 16 + l15) * 8];
            #pragma unroll
            for (int fn = 0; fn < 4; ++fn) {
                int n = wn * 64 + fn * 16 + l15;
                int r = (n >> 7) + ky, c2 = (n & 127) + kx;
                bfv[fn] = *(const short8*)&inT[(r * 130 + c2) * 40 + kg * 8];
            }
            #pragma unroll
            for (int fm = 0; fm < 4; ++fm)
                #pragma unroll
                for (int fn = 0; fn < 4; ++fn)
                    acc[fm][fn] = __builtin_amdgcn_mfma_f32_16x16x32_bf16(af[fm], bfv[fn], acc[fm][fn], 0, 0, 0);
        }
        __syncthreads();
    }

    unsigned short* pt = wc;
    #pragma unroll
    for (int fm = 0; fm < 4; ++fm) {
        #pragma unroll
        for (int r = 0; r < 4; ++r) {
            const int col = fm * 16 + kg * 4 + r;
            const int co  = wm * 64 + col;
            const float bb = b2[co];
            float ls = 0.f, lq = 0.f;
            #pragma unroll
            for (int fn = 0; fn < 4; ++fn) {
                float v = acc[fm][fn][r] + bb;
                ls += v; lq += v * v;
            }
            #pragma unroll
            for (int m = 1; m < 16; m <<= 1) {
                ls += __shfl_xor(ls, m, 64);
                lq += __shfl_xor(lq, m, 64);
            }
            if (l15 == 0) { atomicAdd(&redS[co], ls); atomicAdd(&redQ[co], lq); }
        }
    }
    if (wm == 0) {
        #pragma unroll
        for (int fm = 0; fm < 4; ++fm)
            #pragma unroll
            for (int r = 0; r < 4; ++r) {
                const int col = fm * 16 + kg * 4 + r;
                const float bb = b2[col];
                const int xr = ((col >> 2) & 3) << 4;
                #pragma unroll
                for (int fn = 0; fn < 4; ++fn) {
                    int n = wn * 64 + fn * 16 + l15;
                    pt[col * 512 + (n ^ xr)] = bfbits(acc[fm][fn][r] + bb);
                }
            }
    }
    __syncthreads();
    if (tid < 128) { atomicAdd(&sum2[tid], redS[tid]); atomicAdd(&sq2[tid], redQ[tid]); }
    {
        unsigned short* y2u = (unsigned short*)y2;
        int co_l = tid >> 4, sub = tid & 15;
        int xr = ((co_l >> 2) & 3) << 4;
        size_t base = (((size_t)b * C1_ + co_l) * H_ + y0) * (size_t)W_ + sub * 8;
        #pragma unroll
        for (int j = 0; j < 4; ++j) {
            int p = j * 128 + sub * 8;
            *(short8*)&y2u[base + (size_t)j * W_] = *(short8*)&pt[co_l * 512 + (p ^ xr)];
        }
    }
    __syncthreads();
    if (wm == 1) {
        #pragma unroll
        for (int fm = 0; fm < 4; ++fm)
            #pragma unroll
            for (int r = 0; r < 4; ++r) {
                const int col = fm * 16 + kg * 4 + r;
                const float bb = b2[64 + col];
                const int xr = ((col >> 2) & 3) << 4;
                #pragma unroll
                for (int fn = 0; fn < 4; ++fn) {
                    int n = wn * 64 + fn * 16 + l15;
                    pt[col * 512 + (n ^ xr)] = bfbits(acc[fm][fn][r] + bb);
                }
            }
    }
    __syncthreads();
    {
        unsigned short* y2u = (unsigned short*)y2;
        int co_l = tid >> 4, sub = tid & 15;
        int xr = ((co_l >> 2) & 3) << 4;
        size_t base = (((size_t)b * C1_ + 64 + co_l) * H_ + y0) * (size_t)W_ + sub * 8;
        #pragma unroll
        for (int j = 0; j < 4; ++j) {
            int p = j * 128 + sub * 8;
            *(short8*)&y2u[base + (size_t)j * W_] = *(short8*)&pt[co_l * 512 + (p ^ xr)];
        }
    }
}

// ---------------- lateral path: maxpool2 + conv3x3(2->2) pad1 ----------------
__global__ __launch_bounds__(256) void poolconv_k(const float* __restrict__ out5,
                                                  const float* __restrict__ wl,
                                                  const float* __restrict__ bl,
                                                  float* __restrict__ ds) {
    int idx = blockIdx.x * 256 + threadIdx.x;
    int j = idx & 63;
    int i = (idx >> 6) & 63;
    int c = (idx >> 12) & 1;
    int b = idx >> 13;
    float acc = bl[c];
    #pragma unroll
    for (int ci = 0; ci < 2; ++ci) {
        const float* in = out5 + ((size_t)b * 5 + ci) * HW_;
        #pragma unroll
        for (int ky = 0; ky < 3; ++ky) {
            int ii = i + ky - 1;
            if (ii < 0 || ii > 63) continue;
            #pragma unroll
            for (int kx = 0; kx < 3; ++kx) {
                int jj = j + kx - 1;
                if (jj < 0 || jj > 63) continue;
                const float* p = in + (2 * ii) * W_ + 2 * jj;
                float pooled = fmaxf(fmaxf(p[0], p[1]), fmaxf(p[W_], p[W_ + 1]));
                acc += pooled * wl[(c * 2 + ci) * 9 + ky * 3 + kx];
            }
        }
    }
    ds[idx] = acc;
}

// ---------------- final: conv1x1(inline BN2+ReLU) + upsample + softmax + sigmoids, 8 px/thr ----
__global__ __launch_bounds__(256) void final_k(const float* __restrict__ out5,
                                               const __hip_bfloat16* __restrict__ y2,
                                               const float* __restrict__ g2,
                                               const float* __restrict__ be2,
                                               const float* __restrict__ sum2,
                                               const float* __restrict__ sq2,
                                               const float* __restrict__ w3,
                                               const float* __restrict__ b3,
                                               const float* __restrict__ dsb,
                                               float* __restrict__ out) {
    __shared__ float w3s[256], s2s[128], t2s[128];
    int tid = threadIdx.x;
    w3s[tid] = w3[tid];
    if (tid < 128) {
        const float N = (float)(B_ * HW_);
        float m = sum2[tid] / N;
        float v = sq2[tid] / N - m * m;
        float sc = g2[tid] / sqrtf(v + 1e-5f);
        s2s[tid] = sc;
        t2s[tid] = be2[tid] - sc * m;
    }
    __syncthreads();
    int gid = blockIdx.x * 256 + tid;       // 65536 threads, 8 px each
    int b = gid >> 11;
    int rem = gid & 2047;
    int y = rem >> 4;
    int x0 = (rem & 15) * 8;
    int p = y * W_ + x0;

    const unsigned short* yp = (const unsigned short*)y2 + (size_t)b * C1_ * HW_ + p;
    float jm0[8], jm1[8];
    #pragma unroll
    for (int i = 0; i < 8; ++i) { jm0[i] = b3[0]; jm1[i] = b3[1]; }
    for (int ci = 0; ci < 128; ++ci) {
        short8 v = *(const short8*)(yp + (size_t)ci * HW_);
        float sc = s2s[ci], tc = t2s[ci];
        float w0 = w3s[ci], w1c = w3s[128 + ci];
        #pragma unroll
        for (int i = 0; i < 8; ++i) {
            float h = fmaxf(fmaf(sc, bf2f((unsigned short)v[i]), tc), 0.f);
            jm0[i] = fmaf(h, w0, jm0[i]);
            jm1[i] = fmaf(h, w1c, jm1[i]);
        }
    }

    const float fo = (float)(63.0 / 127.0);
    float sy = (float)y * fo;
    int ly = (int)floorf(sy); ly = ly < 0 ? 0 : (ly > 62 ? 62 : ly);
    float wy = sy - (float)ly;
    const float* dbase = dsb + ((size_t)b * 2) * 4096;
    float sig[8];
    #pragma unroll
    for (int i = 0; i < 8; ++i) {
        int x = x0 + i;
        float sx = (float)x * fo;
        int lx = (int)floorf(sx); lx = lx < 0 ? 0 : (lx > 62 ? 62 : lx);
        float wx = sx - (float)lx;
        float up[2];
        #pragma unroll
        for (int c = 0; c < 2; ++c) {
            const float* d = dbase + c * 4096;
            float d00 = d[ly * 64 + lx],       d01 = d[ly * 64 + lx + 1];
            float d10 = d[(ly + 1) * 64 + lx], d11 = d[(ly + 1) * 64 + lx + 1];
            up[c] = (1.f - wy) * ((1.f - wx) * d00 + wx * d01) + wy * ((1.f - wx) * d10 + wx * d11);
        }
        float dlt = (jm1[i] + up[1]) - (jm0[i] + up[0]);
        sig[i] = 1.f / (1.f + expf(-dlt));
    }
    *(f32x4*)&out[(size_t)b * HW_ + p]     = (f32x4){sig[0], sig[1], sig[2], sig[3]};
    *(f32x4*)&out[(size_t)b * HW_ + p + 4] = (f32x4){sig[4], sig[5], sig[6], sig[7]};

    #pragma unroll
    for (int h2 = 0; h2 < 2; ++h2) {
        f32x4 lm = *(const f32x4*)&out5[((size_t)b * 5 + 2) * HW_ + p + h2 * 4];
        f32x4 r;
        #pragma unroll
        for (int i = 0; i < 4; ++i) r[i] = 1.f / (1.f + expf(-lm[i]));
        *(f32x4*)&out[524288 + (size_t)b * HW_ + p + h2 * 4] = r;
    }
    #pragma unroll
    for (int h2 = 0; h2 < 2; ++h2) {
        f32x4 o3 = *(const f32x4*)&out5[((size_t)b * 5 + 3) * HW_ + p + h2 * 4];
        f32x4 o4 = *(const f32x4*)&out5[((size_t)b * 5 + 4) * HW_ + p + h2 * 4];
        f32x4 r3, r4;
        #pragma unroll
        for (int i = 0; i < 4; ++i) {
            r3[i] = 1.f / (1.f + expf(-o3[i])) - 0.5f;
            r4[i] = 1.f / (1.f + expf(-o4[i])) - 0.5f;
        }
        *(f32x4*)&out[1048576 + ((size_t)b * 2 + 0) * HW_ + p + h2 * 4] = r3;
        *(f32x4*)&out[1048576 + ((size_t)b * 2 + 1) * HW_ + p + h2 * 4] = r4;
    }
}

extern "C" void kernel_launch(void* const* d_in, const int* in_sizes, int n_in,
                              void* d_out, int out_size, void* d_ws, size_t ws_size,
                              hipStream_t stream) {
    const float* out5 = (const float*)d_in[0];
    const float* jmap = (const float*)d_in[1];
    const float* w1   = (const float*)d_in[2];
    const float* b1   = (const float*)d_in[3];
    const float* g1   = (const float*)d_in[4];
    const float* be1  = (const float*)d_in[5];
    const float* w2   = (const float*)d_in[6];
    const float* b2   = (const float*)d_in[7];
    const float* g2   = (const float*)d_in[8];
    const float* be2  = (const float*)d_in[9];
    const float* w3   = (const float*)d_in[10];
    const float* b3   = (const float*)d_in[11];
    const float* wl   = (const float*)d_in[12];
    const float* bl   = (const float*)d_in[13];
    const float* ga   = (const float*)d_in[14];
    const float* gb   = (const float*)d_in[15];
    float* out = (float*)d_out;

    // ws layout (~135.3 MB):
    //   [0, 134217728)           y2 bf16
    //   [134217728, +294912)     w2t2 } overlapped later by dsb (disjoint lifetimes)
    //   [134512640, +8192)       w1t  }
    //   [134217728, +1048576)    dsb (poolconv out; written after conv2 done)
    //   [135266304, +4096)       stats
    char* ws = (char*)d_ws;
    __hip_bfloat16* y2 = (__hip_bfloat16*)ws;
    unsigned short* w2t2 = (unsigned short*)(ws + 134217728);
    unsigned short* w1t  = (unsigned short*)(ws + 134512640);
    float* dsb = (float*)(ws + 134217728);
    float* st  = (float*)(ws + 135266304);
    float* sum1 = st;        float* sq1 = st + 128;
    float* sum2 = st + 256;  float* sq2 = st + 384;

    float* gout = out + 2097152;   // gauss target region of d_out

    prep_all<<<594, 256, 0, stream>>>(w2, w1, w2t2, w1t, st);
    gauss_m<<<dim3(64, 32), 256, 0, stream>>>(jmap, gout, ga, gb);
    conv1stats_mfma<<<1024, 1024, 0, stream>>>(out5, b1, w1t, sum1, sq1);
    conv2_mfma<<<1024, 1024, 0, stream>>>(out5, b1, g1, be1, sum1, sq1, w2t2, w1t, b2, y2, sum2, sq2);
    poolconv_k<<<1024, 256, 0, stream>>>(out5, wl, bl, dsb);
    final_k<<<256, 256, 0, stream>>>(out5, y2, g2, be2, sum2, sq2, w3, b3, dsb, out);
}

// Round 13
// 343.364 us; speedup vs baseline: 1.9299x; 1.0015x over previous
//
#include <hip/hip_runtime.h>
#include <hip/hip_bf16.h>

#define B_   32
#define H_   128
#define W_   128
#define HW_  16384
#define C1_  128

typedef __attribute__((ext_vector_type(8))) short short8;
typedef __attribute__((ext_vector_type(4))) short short4v;
typedef __attribute__((ext_vector_type(4))) float f32x4;

static __device__ __forceinline__ unsigned short bfbits(float f) {
    __hip_bfloat16 h = __float2bfloat16(f);
    return *reinterpret_cast<unsigned short*>(&h);
}
static __device__ __forceinline__ float bf2f(unsigned int u) {
    union { unsigned int ui; float f; } cv; cv.ui = u << 16; return cv.f;
}
static __device__ __forceinline__ unsigned short bftrunc(float f) {
    unsigned u = __builtin_bit_cast(unsigned, f);
    return (unsigned short)((u + 0x8000u) >> 16);
}
// pack two floats to bf16 pair (lo = a, hi = b), round-half-up (r7-validated)
static __device__ __forceinline__ unsigned packbf2(float a, float b) {
    unsigned ua = __builtin_bit_cast(unsigned, a) + 0x8000u;
    unsigned ub = __builtin_bit_cast(unsigned, b) + 0x8000u;
    return __builtin_amdgcn_perm(ub, ua, 0x07060302u);
}

// ---- merged prep (w2t2 r6 layout, w1t, zero stats) + gaussian splat ----
// blocks [0,594): prep; blocks [594,2642): gauss (64 x-tiles x 32 batches)
__global__ __launch_bounds__(256) void prep_gauss(const float* __restrict__ w2,
                                                  const float* __restrict__ w1,
                                                  unsigned short* __restrict__ w2t2,
                                                  unsigned short* __restrict__ w1t,
                                                  float* __restrict__ st,
                                                  const float* __restrict__ jmap,
                                                  float* __restrict__ outg,
                                                  const float* __restrict__ ga,
                                                  const float* __restrict__ gb) {
    __shared__ float k1[33];
    __shared__ float vrow[2][128];
    int bid = blockIdx.x;
    int tid = threadIdx.x;
    if (bid < 594) {
        int idx = bid * 256 + tid;
        if (idx < 147456) {
            int e  = idx & 7;
            int co = (idx >> 3) & 127;
            int kg = (idx >> 10) & 3;
            int t  = idx >> 12;          // 0..35
            int kk = t % 9, cc = t / 9;
            int ci = cc * 32 + kg * 8 + e;
            w2t2[idx] = bfbits(w2[((size_t)co * 128 + ci) * 9 + kk]);
        } else if (idx < 151552) {
            int i2 = idx - 147456;
            int k = i2 & 31, ci = i2 >> 5;
            w1t[i2] = (k < 18) ? bfbits(w1[ci * 18 + k]) : (unsigned short)0;
        } else if (idx < 152064) {
            st[idx - 151552] = 0.f;
        }
        return;
    }
    // ---- gauss: v-pass + h-pass fused (±16 window; tail < 3e-14) ----
    int g2 = bid - 594;
    int bx = g2 & 63, b = g2 >> 6;
    float a = ga[0] / (gb[0] * gb[0]);
    if (tid < 33) { float d = (float)tid - 16.f; k1[tid] = expf(a * d * d); }
    __syncthreads();
    int ly = tid >> 7;
    int y = bx * 2 + ly;
    int x = tid & 127;
    const float* m = jmap + (size_t)b * HW_;
    int lo = y - 16; if (lo < 0) lo = 0;
    int hi = y + 16; if (hi > 127) hi = 127;
    float s = 0.f;
    for (int yy = lo; yy <= hi; ++yy) {
        float mv = m[yy * W_ + x];
        s += (mv == 1.0f) ? k1[yy - y + 16] : 0.f;
    }
    vrow[ly][x] = s;
    __syncthreads();
    int lo2 = x - 16; if (lo2 < 0) lo2 = 0;
    int hi2 = x + 16; if (hi2 > 127) hi2 = 127;
    float s2 = 0.f;
    for (int xx = lo2; xx <= hi2; ++xx)
        s2 += k1[xx - x + 16] * vrow[ly][xx];
    float g = m[y * W_ + x] + s2;
    g = (g <= 0.05f) ? 0.f : fminf(g, 1.0f);
    outg[(size_t)b * HW_ + y * W_ + x] = g;
}

// ---------------- conv1 stats via MFMA (h = conv1+b1) ----------------
__global__ __launch_bounds__(1024) void conv1stats_mfma(
    const float* __restrict__ out5,
    const float* __restrict__ b1,
    const unsigned short* __restrict__ w1t,
    float* __restrict__ sum1,
    float* __restrict__ sq1)
{
    __shared__ unsigned short w1l[4096];
    __shared__ float b1sh[128], redS[128], redQ[128];
    const int tid = threadIdx.x;
    const int b  = blockIdx.x >> 5;
    const int y0 = (blockIdx.x & 31) * 4;
    const int lane = tid & 63, w = tid >> 6;   // 16 waves
    const int wm = w & 1;                      // ci half
    const int njb = w >> 1;                    // pos-tile base (0..7)
    const int l15 = lane & 15, kg = lane >> 4;

    if (tid < 128) { redS[tid] = 0.f; redQ[tid] = 0.f; b1sh[tid] = b1[tid]; }
    if (tid < 512) *(short8*)&w1l[tid * 8] = *(const short8*)&w1t[tid * 8];

    const float* in0 = out5 + (size_t)b * 5 * HW_;
    const float* in1 = in0 + HW_;
    short8 bfrag[4];
    #pragma unroll
    for (int k = 0; k < 4; ++k) {
        short8 f = (short8){0,0,0,0,0,0,0,0};
        int q = (njb + k * 8) * 16 + l15;      // 0..511
        int gy = y0 + (q >> 7), gx = q & 127;
        #pragma unroll
        for (int kk = 0; kk < 8; ++kk) {
            int kidx = kg * 8 + kk;
            unsigned short v = 0;
            if (kidx < 18) {
                int ch = (kidx >= 9) ? 1 : 0;
                int km = kidx - ch * 9;
                int ky = km / 3, kx = km - ky * 3;
                int yy = gy + ky - 1, xx = gx + kx - 1;
                if ((unsigned)yy < 128u && (unsigned)xx < 128u)
                    v = bfbits((ch ? in1 : in0)[yy * W_ + xx]);
            }
            f[kk] = (short)v;
        }
        bfrag[k] = f;
    }
    __syncthreads();

    #pragma unroll
    for (int cc = 0; cc < 4; ++cc) {
        short8 a1 = *(const short8*)&w1l[(cc * 32 + wm * 16 + l15) * 32 + kg * 8];
        float ls[4] = {0.f, 0.f, 0.f, 0.f}, lq[4] = {0.f, 0.f, 0.f, 0.f};
        #pragma unroll
        for (int k = 0; k < 4; ++k) {
            f32x4 hacc = (f32x4){0.f, 0.f, 0.f, 0.f};
            hacc = __builtin_amdgcn_mfma_f32_16x16x32_bf16(a1, bfrag[k], hacc, 0, 0, 0);
            #pragma unroll
            for (int rr = 0; rr < 4; ++rr) {
                float h = hacc[rr] + b1sh[cc * 32 + wm * 16 + kg * 4 + rr];
                ls[rr] += h; lq[rr] += h * h;
            }
        }
        #pragma unroll
        for (int rr = 0; rr < 4; ++rr) {
            #pragma unroll
            for (int m = 1; m < 16; m <<= 1) {
                ls[rr] += __shfl_xor(ls[rr], m, 64);
                lq[rr] += __shfl_xor(lq[rr], m, 64);
            }
            if (l15 == 0) {
                int ci = cc * 32 + wm * 16 + kg * 4 + rr;
                atomicAdd(&redS[ci], ls[rr]);
                atomicAdd(&redQ[ci], lq[rr]);
            }
        }
    }
    __syncthreads();
    if (tid < 128) { atomicAdd(&sum1[tid], redS[tid]); atomicAdd(&sq1[tid], redQ[tid]); }
}

// ---------------- conv2 via MFMA: GOLDEN r6 structure + inline BN1 + packbf2 h1 ----------
__global__ __launch_bounds__(1024) void conv2_mfma(
    const float* __restrict__ out5,
    const float* __restrict__ b1,
    const float* __restrict__ g1,
    const float* __restrict__ be1,
    const float* __restrict__ sum1,
    const float* __restrict__ sq1,
    const unsigned short* __restrict__ w2t2,
    const unsigned short* __restrict__ w1t,
    const float* __restrict__ b2,
    __hip_bfloat16* __restrict__ y2,
    float* __restrict__ sum2,
    float* __restrict__ sq2)
{
    __shared__ unsigned short inT[31200];
    __shared__ unsigned short wc[36864];
    __shared__ unsigned short w1l[4096];
    __shared__ float s1sh[128], t1sh[128], redS[128], redQ[128];

    const int tid = threadIdx.x;
    const int b  = blockIdx.x >> 5;
    const int y0 = (blockIdx.x & 31) * 4;
    const int lane = tid & 63, w = tid >> 6;
    const int wm = w & 1, wn = w >> 1;
    const int l15 = lane & 15, kg = lane >> 4;

    if (tid < 128) {
        redS[tid] = 0.f; redQ[tid] = 0.f;
        const float N = (float)(B_ * HW_);
        float m = sum1[tid] / N;
        float v = sq1[tid] / N - m * m;
        float sc = g1[tid] / sqrtf(v + 1e-5f);
        s1sh[tid] = sc;
        t1sh[tid] = fmaf(sc, b1[tid] - m, be1[tid]);
    }
    if (tid < 512) *(short8*)&w1l[tid * 8] = *(const short8*)&w1t[tid * 8];

    const float* in0 = out5 + (size_t)b * 5 * HW_;
    const float* in1 = in0 + HW_;
    const int mi  = wm;
    const int njb = w >> 1;
    short8 bfrag[7];
    #pragma unroll
    for (int k = 0; k < 7; ++k) {
        short8 f = (short8){0,0,0,0,0,0,0,0};
        int nj = njb + k * 8;
        int q  = nj * 16 + l15;
        if (nj <= 48 && q < 780) {
            int r = q / 130, c = q - r * 130;
            int gy = y0 - 1 + r, gx = c - 1;
            #pragma unroll
            for (int kk = 0; kk < 8; ++kk) {
                int kidx = kg * 8 + kk;
                unsigned short v = 0;
                if (kidx < 18) {
                    int ch = (kidx >= 9) ? 1 : 0;
                    int km = kidx - ch * 9;
                    int ky = km / 3, kx = km - ky * 3;
                    int yy = gy + ky - 1, xx = gx + kx - 1;
                    if ((unsigned)yy < 128u && (unsigned)xx < 128u)
                        v = bfbits((ch ? in1 : in0)[yy * W_ + xx]);
                }
                f[kk] = (short)v;
            }
        }
        bfrag[k] = f;
    }
    __syncthreads();

    f32x4 acc[4][4];
    #pragma unroll
    for (int fm = 0; fm < 4; ++fm)
        #pragma unroll
        for (int fn = 0; fn < 4; ++fn) acc[fm][fn] = (f32x4){0.f, 0.f, 0.f, 0.f};

    for (int cc = 0; cc < 4; ++cc) {
        const unsigned short* wsrc = w2t2 + cc * 36864;
        #pragma unroll
        for (int u = 0; u < 4; ++u)
            __builtin_amdgcn_global_load_lds(
                (const unsigned int*)(wsrc + (u * 1024 + tid) * 8),
                (unsigned int*)&wc[(u * 1024 + tid) * 8], 16, 0, 0);
        if (tid < 512)
            __builtin_amdgcn_global_load_lds(
                (const unsigned int*)(wsrc + (4096 + tid) * 8),
                (unsigned int*)&wc[(4096 + tid) * 8], 16, 0, 0);

        short8 a1 = *(const short8*)&w1l[(cc * 32 + mi * 16 + l15) * 32 + kg * 8];
        #pragma unroll
        for (int k = 0; k < 7; ++k) {
            int nj = njb + k * 8;
            if (nj <= 48) {
                int q = nj * 16 + l15;
                f32x4 hacc = (f32x4){0.f, 0.f, 0.f, 0.f};
                hacc = __builtin_amdgcn_mfma_f32_16x16x32_bf16(a1, bfrag[k], hacc, 0, 0, 0);
                int r = q / 130, c = q - r * 130;
                int gy = y0 - 1 + r;
                bool zero = (q >= 780) || ((unsigned)gy >= 128u) || (c == 0) || (c == 129);
                int cigb = cc * 32 + mi * 16 + kg * 4;
                float h0 = fmaxf(fmaf(s1sh[cigb],     hacc[0], t1sh[cigb]),     0.f);
                float h1 = fmaxf(fmaf(s1sh[cigb + 1], hacc[1], t1sh[cigb + 1]), 0.f);
                float h2 = fmaxf(fmaf(s1sh[cigb + 2], hacc[2], t1sh[cigb + 2]), 0.f);
                float h3 = fmaxf(fmaf(s1sh[cigb + 3], hacc[3], t1sh[cigb + 3]), 0.f);
                unsigned long long pk = zero ? 0ull
                    : (((unsigned long long)packbf2(h2, h3)) << 32) | packbf2(h0, h1);
                if (q < 780)
                    *(unsigned long long*)&inT[(r * 130 + c) * 40 + mi * 16 + kg * 4] = pk;
            }
        }
        __syncthreads();

        #pragma unroll
        for (int kk = 0; kk < 9; ++kk) {
            const int ky = kk / 3, kx = kk % 3;
            short8 af[4], bfv[4];
            #pragma unroll
            for (int fm = 0; fm < 4; ++fm)
                af[fm] = *(const short8*)&wc[((kk * 4 + kg) * 128 + wm * 64 + fm * 16 + l15) * 8];
            #pragma unroll
            for (int fn = 0; fn < 4; ++fn) {
                int n = wn * 64 + fn * 16 + l15;
                int r = (n >> 7) + ky, c2 = (n & 127) + kx;
                bfv[fn] = *(const short8*)&inT[(r * 130 + c2) * 40 + kg * 8];
            }
            #pragma unroll
            for (int fm = 0; fm < 4; ++fm)
                #pragma unroll
                for (int fn = 0; fn < 4; ++fn)
                    acc[fm][fn] = __builtin_amdgcn_mfma_f32_16x16x32_bf16(af[fm], bfv[fn], acc[fm][fn], 0, 0, 0);
        }
        __syncthreads();
    }

    unsigned short* pt = wc;
    #pragma unroll
    for (int fm = 0; fm < 4; ++fm) {
        #pragma unroll
        for (int r = 0; r < 4; ++r) {
            const int col = fm * 16 + kg * 4 + r;
            const int co  = wm * 64 + col;
            const float bb = b2[co];
            float ls = 0.f, lq = 0.f;
            #pragma unroll
            for (int fn = 0; fn < 4; ++fn) {
                float v = acc[fm][fn][r] + bb;
                ls += v; lq += v * v;
            }
            #pragma unroll
            for (int m = 1; m < 16; m <<= 1) {
                ls += __shfl_xor(ls, m, 64);
                lq += __shfl_xor(lq, m, 64);
            }
            if (l15 == 0) { atomicAdd(&redS[co], ls); atomicAdd(&redQ[co], lq); }
        }
    }
    if (wm == 0) {
        #pragma unroll
        for (int fm = 0; fm < 4; ++fm)
            #pragma unroll
            for (int r = 0; r < 4; ++r) {
                const int col = fm * 16 + kg * 4 + r;
                const float bb = b2[col];
                const int xr = ((col >> 2) & 3) << 4;
                #pragma unroll
                for (int fn = 0; fn < 4; ++fn) {
                    int n = wn * 64 + fn * 16 + l15;
                    pt[col * 512 + (n ^ xr)] = bftrunc(acc[fm][fn][r] + bb);
                }
            }
    }
    __syncthreads();
    if (tid < 128) { atomicAdd(&sum2[tid], redS[tid]); atomicAdd(&sq2[tid], redQ[tid]); }
    {
        unsigned short* y2u = (unsigned short*)y2;
        int co_l = tid >> 4, sub = tid & 15;
        int xr = ((co_l >> 2) & 3) << 4;
        size_t base = (((size_t)b * C1_ + co_l) * H_ + y0) * (size_t)W_ + sub * 8;
        #pragma unroll
        for (int j = 0; j < 4; ++j) {
            int p = j * 128 + sub * 8;
            *(short8*)&y2u[base + (size_t)j * W_] = *(short8*)&pt[co_l * 512 + (p ^ xr)];
        }
    }
    __syncthreads();
    if (wm == 1) {
        #pragma unroll
        for (int fm = 0; fm < 4; ++fm)
            #pragma unroll
            for (int r = 0; r < 4; ++r) {
                const int col = fm * 16 + kg * 4 + r;
                const float bb = b2[64 + col];
                const int xr = ((col >> 2) & 3) << 4;
                #pragma unroll
                for (int fn = 0; fn < 4; ++fn) {
                    int n = wn * 64 + fn * 16 + l15;
                    pt[col * 512 + (n ^ xr)] = bftrunc(acc[fm][fn][r] + bb);
                }
            }
    }
    __syncthreads();
    {
        unsigned short* y2u = (unsigned short*)y2;
        int co_l = tid >> 4, sub = tid & 15;
        int xr = ((co_l >> 2) & 3) << 4;
        size_t base = (((size_t)b * C1_ + 64 + co_l) * H_ + y0) * (size_t)W_ + sub * 8;
        #pragma unroll
        for (int j = 0; j < 4; ++j) {
            int p = j * 128 + sub * 8;
            *(short8*)&y2u[base + (size_t)j * W_] = *(short8*)&pt[co_l * 512 + (p ^ xr)];
        }
    }
}

// ---------------- lateral path: maxpool2 + conv3x3(2->2) pad1 ----------------
__global__ __launch_bounds__(256) void poolconv_k(const float* __restrict__ out5,
                                                  const float* __restrict__ wl,
                                                  const float* __restrict__ bl,
                                                  float* __restrict__ ds) {
    int idx = blockIdx.x * 256 + threadIdx.x;
    int j = idx & 63;
    int i = (idx >> 6) & 63;
    int c = (idx >> 12) & 1;
    int b = idx >> 13;
    float acc = bl[c];
    #pragma unroll
    for (int ci = 0; ci < 2; ++ci) {
        const float* in = out5 + ((size_t)b * 5 + ci) * HW_;
        #pragma unroll
        for (int ky = 0; ky < 3; ++ky) {
            int ii = i + ky - 1;
            if (ii < 0 || ii > 63) continue;
            #pragma unroll
            for (int kx = 0; kx < 3; ++kx) {
                int jj = j + kx - 1;
                if (jj < 0 || jj > 63) continue;
                const float* p = in + (2 * ii) * W_ + 2 * jj;
                float pooled = fmaxf(fmaxf(p[0], p[1]), fmaxf(p[W_], p[W_ + 1]));
                acc += pooled * wl[(c * 2 + ci) * 9 + ky * 3 + kx];
            }
        }
    }
    ds[idx] = acc;
}

// ---------------- final: conv1x1(inline BN2+ReLU) + upsample + softmax + sigmoids, 8 px/thr ----
__global__ __launch_bounds__(256) void final_k(const float* __restrict__ out5,
                                               const __hip_bfloat16* __restrict__ y2,
                                               const float* __restrict__ g2,
                                               const float* __restrict__ be2,
                                               const float* __restrict__ sum2,
                                               const float* __restrict__ sq2,
                                               const float* __restrict__ w3,
                                               const float* __restrict__ b3,
                                               const float* __restrict__ dsb,
                                               float* __restrict__ out) {
    __shared__ float w3s[256], s2s[128], t2s[128];
    int tid = threadIdx.x;
    w3s[tid] = w3[tid];
    if (tid < 128) {
        const float N = (float)(B_ * HW_);
        float m = sum2[tid] / N;
        float v = sq2[tid] / N - m * m;
        float sc = g2[tid] / sqrtf(v + 1e-5f);
        s2s[tid] = sc;
        t2s[tid] = be2[tid] - sc * m;
    }
    __syncthreads();
    int gid = blockIdx.x * 256 + tid;       // 65536 threads, 8 px each
    int b = gid >> 11;
    int rem = gid & 2047;
    int y = rem >> 4;
    int x0 = (rem & 15) * 8;
    int p = y * W_ + x0;

    const unsigned short* yp = (const unsigned short*)y2 + (size_t)b * C1_ * HW_ + p;
    float jm0[8], jm1[8];
    #pragma unroll
    for (int i = 0; i < 8; ++i) { jm0[i] = b3[0]; jm1[i] = b3[1]; }
    for (int ci = 0; ci < 128; ++ci) {
        short8 v = *(const short8*)(yp + (size_t)ci * HW_);
        float sc = s2s[ci], tc = t2s[ci];
        float w0 = w3s[ci], w1c = w3s[128 + ci];
        #pragma unroll
        for (int i = 0; i < 8; ++i) {
            float h = fmaxf(fmaf(sc, bf2f((unsigned short)v[i]), tc), 0.f);
            jm0[i] = fmaf(h, w0, jm0[i]);
            jm1[i] = fmaf(h, w1c, jm1[i]);
        }
    }

    const float fo = (float)(63.0 / 127.0);
    float sy = (float)y * fo;
    int ly = (int)floorf(sy); ly = ly < 0 ? 0 : (ly > 62 ? 62 : ly);
    float wy = sy - (float)ly;
    const float* dbase = dsb + ((size_t)b * 2) * 4096;
    float sig[8];
    #pragma unroll
    for (int i = 0; i < 8; ++i) {
        int x = x0 + i;
        float sx = (float)x * fo;
        int lx = (int)floorf(sx); lx = lx < 0 ? 0 : (lx > 62 ? 62 : lx);
        float wx = sx - (float)lx;
        float up[2];
        #pragma unroll
        for (int c = 0; c < 2; ++c) {
            const float* d = dbase + c * 4096;
            float d00 = d[ly * 64 + lx],       d01 = d[ly * 64 + lx + 1];
            float d10 = d[(ly + 1) * 64 + lx], d11 = d[(ly + 1) * 64 + lx + 1];
            up[c] = (1.f - wy) * ((1.f - wx) * d00 + wx * d01) + wy * ((1.f - wx) * d10 + wx * d11);
        }
        float dlt = (jm1[i] + up[1]) - (jm0[i] + up[0]);
        sig[i] = 1.f / (1.f + expf(-dlt));
    }
    *(f32x4*)&out[(size_t)b * HW_ + p]     = (f32x4){sig[0], sig[1], sig[2], sig[3]};
    *(f32x4*)&out[(size_t)b * HW_ + p + 4] = (f32x4){sig[4], sig[5], sig[6], sig[7]};

    #pragma unroll
    for (int h2 = 0; h2 < 2; ++h2) {
        f32x4 lm = *(const f32x4*)&out5[((size_t)b * 5 + 2) * HW_ + p + h2 * 4];
        f32x4 r;
        #pragma unroll
        for (int i = 0; i < 4; ++i) r[i] = 1.f / (1.f + expf(-lm[i]));
        *(f32x4*)&out[524288 + (size_t)b * HW_ + p + h2 * 4] = r;
    }
    #pragma unroll
    for (int h2 = 0; h2 < 2; ++h2) {
        f32x4 o3 = *(const f32x4*)&out5[((size_t)b * 5 + 3) * HW_ + p + h2 * 4];
        f32x4 o4 = *(const f32x4*)&out5[((size_t)b * 5 + 4) * HW_ + p + h2 * 4];
        f32x4 r3, r4;
        #pragma unroll
        for (int i = 0; i < 4; ++i) {
            r3[i] = 1.f / (1.f + expf(-o3[i])) - 0.5f;
            r4[i] = 1.f / (1.f + expf(-o4[i])) - 0.5f;
        }
        *(f32x4*)&out[1048576 + ((size_t)b * 2 + 0) * HW_ + p + h2 * 4] = r3;
        *(f32x4*)&out[1048576 + ((size_t)b * 2 + 1) * HW_ + p + h2 * 4] = r4;
    }
}

extern "C" void kernel_launch(void* const* d_in, const int* in_sizes, int n_in,
                              void* d_out, int out_size, void* d_ws, size_t ws_size,
                              hipStream_t stream) {
    const float* out5 = (const float*)d_in[0];
    const float* jmap = (const float*)d_in[1];
    const float* w1   = (const float*)d_in[2];
    const float* b1   = (const float*)d_in[3];
    const float* g1   = (const float*)d_in[4];
    const float* be1  = (const float*)d_in[5];
    const float* w2   = (const float*)d_in[6];
    const float* b2   = (const float*)d_in[7];
    const float* g2   = (const float*)d_in[8];
    const float* be2  = (const float*)d_in[9];
    const float* w3   = (const float*)d_in[10];
    const float* b3   = (const float*)d_in[11];
    const float* wl   = (const float*)d_in[12];
    const float* bl   = (const float*)d_in[13];
    const float* ga   = (const float*)d_in[14];
    const float* gb   = (const float*)d_in[15];
    float* out = (float*)d_out;

    // ws layout (~135.3 MB):
    //   [0, 134217728)           y2 bf16
    //   [134217728, +294912)     w2t2 } overlapped later by dsb (disjoint lifetimes)
    //   [134512640, +8192)       w1t  }
    //   [134217728, +1048576)    dsb (poolconv out; written after conv2 done)
    //   [135266304, +4096)       stats
    char* ws = (char*)d_ws;
    __hip_bfloat16* y2 = (__hip_bfloat16*)ws;
    unsigned short* w2t2 = (unsigned short*)(ws + 134217728);
    unsigned short* w1t  = (unsigned short*)(ws + 134512640);
    float* dsb = (float*)(ws + 134217728);
    float* st  = (float*)(ws + 135266304);
    float* sum1 = st;        float* sq1 = st + 128;
    float* sum2 = st + 256;  float* sq2 = st + 384;

    float* gout = out + 2097152;   // gauss target region of d_out

    prep_gauss<<<2642, 256, 0, stream>>>(w2, w1, w2t2, w1t, st, jmap, gout, ga, gb);
    conv1stats_mfma<<<1024, 1024, 0, stream>>>(out5, b1, w1t, sum1, sq1);
    conv2_mfma<<<1024, 1024, 0, stream>>>(out5, b1, g1, be1, sum1, sq1, w2t2, w1t, b2, y2, sum2, sq2);
    poolconv_k<<<1024, 256, 0, stream>>>(out5, wl, bl, dsb);
    final_k<<<256, 256, 0, stream>>>(out5, y2, g2, be2, sum2, sq2, w3, b3, dsb, out);
}

// Round 14
// 340.779 us; speedup vs baseline: 1.9445x; 1.0076x over previous
//
#include <hip/hip_runtime.h>
#include <hip/hip_bf16.h>

#define B_   32
#define H_   128
#define W_   128
#define HW_  16384
#define C1_  128

typedef __attribute__((ext_vector_type(8))) short short8;
typedef __attribute__((ext_vector_type(4))) short short4v;
typedef __attribute__((ext_vector_type(4))) float f32x4;

static __device__ __forceinline__ unsigned short bfbits(float f) {
    __hip_bfloat16 h = __float2bfloat16(f);
    return *reinterpret_cast<unsigned short*>(&h);
}
static __device__ __forceinline__ float bf2f(unsigned int u) {
    union { unsigned int ui; float f; } cv; cv.ui = u << 16; return cv.f;
}

// ---- merged prep (w2t2 r6 layout, w1t, zero stats) + gaussian splat ----
// blocks [0,594): prep; blocks [594,2642): gauss (64 x-tiles x 32 batches)
__global__ __launch_bounds__(256) void prep_gauss(const float* __restrict__ w2,
                                                  const float* __restrict__ w1,
                                                  unsigned short* __restrict__ w2t2,
                                                  unsigned short* __restrict__ w1t,
                                                  float* __restrict__ st,
                                                  const float* __restrict__ jmap,
                                                  float* __restrict__ outg,
                                                  const float* __restrict__ ga,
                                                  const float* __restrict__ gb) {
    __shared__ float k1[33];
    __shared__ float vrow[2][128];
    int bid = blockIdx.x;
    int tid = threadIdx.x;
    if (bid < 594) {
        int idx = bid * 256 + tid;
        if (idx < 147456) {
            int e  = idx & 7;
            int co = (idx >> 3) & 127;
            int kg = (idx >> 10) & 3;
            int t  = idx >> 12;          // 0..35
            int kk = t % 9, cc = t / 9;
            int ci = cc * 32 + kg * 8 + e;
            w2t2[idx] = bfbits(w2[((size_t)co * 128 + ci) * 9 + kk]);
        } else if (idx < 151552) {
            int i2 = idx - 147456;
            int k = i2 & 31, ci = i2 >> 5;
            w1t[i2] = (k < 18) ? bfbits(w1[ci * 18 + k]) : (unsigned short)0;
        } else if (idx < 152064) {
            st[idx - 151552] = 0.f;
        }
        return;
    }
    // ---- gauss: v-pass + h-pass fused (±16 window; tail < 3e-14) ----
    int g2 = bid - 594;
    int bx = g2 & 63, b = g2 >> 6;
    float a = ga[0] / (gb[0] * gb[0]);
    if (tid < 33) { float d = (float)tid - 16.f; k1[tid] = expf(a * d * d); }
    __syncthreads();
    int ly = tid >> 7;
    int y = bx * 2 + ly;
    int x = tid & 127;
    const float* m = jmap + (size_t)b * HW_;
    int lo = y - 16; if (lo < 0) lo = 0;
    int hi = y + 16; if (hi > 127) hi = 127;
    float s = 0.f;
    for (int yy = lo; yy <= hi; ++yy) {
        float mv = m[yy * W_ + x];
        s += (mv == 1.0f) ? k1[yy - y + 16] : 0.f;
    }
    vrow[ly][x] = s;
    __syncthreads();
    int lo2 = x - 16; if (lo2 < 0) lo2 = 0;
    int hi2 = x + 16; if (hi2 > 127) hi2 = 127;
    float s2 = 0.f;
    for (int xx = lo2; xx <= hi2; ++xx)
        s2 += k1[xx - x + 16] * vrow[ly][xx];
    float g = m[y * W_ + x] + s2;
    g = (g <= 0.05f) ? 0.f : fminf(g, 1.0f);
    outg[(size_t)b * HW_ + y * W_ + x] = g;
}

// ---------------- conv1 stats via MFMA (h = conv1+b1) ----------------
__global__ __launch_bounds__(1024) void conv1stats_mfma(
    const float* __restrict__ out5,
    const float* __restrict__ b1,
    const unsigned short* __restrict__ w1t,
    float* __restrict__ sum1,
    float* __restrict__ sq1)
{
    __shared__ unsigned short w1l[4096];
    __shared__ float b1sh[128], redS[128], redQ[128];
    const int tid = threadIdx.x;
    const int b  = blockIdx.x >> 5;
    const int y0 = (blockIdx.x & 31) * 4;
    const int lane = tid & 63, w = tid >> 6;   // 16 waves
    const int wm = w & 1;                      // ci half
    const int njb = w >> 1;                    // pos-tile base (0..7)
    const int l15 = lane & 15, kg = lane >> 4;

    if (tid < 128) { redS[tid] = 0.f; redQ[tid] = 0.f; b1sh[tid] = b1[tid]; }
    if (tid < 512) *(short8*)&w1l[tid * 8] = *(const short8*)&w1t[tid * 8];

    const float* in0 = out5 + (size_t)b * 5 * HW_;
    const float* in1 = in0 + HW_;
    short8 bfrag[4];
    #pragma unroll
    for (int k = 0; k < 4; ++k) {
        short8 f = (short8){0,0,0,0,0,0,0,0};
        int q = (njb + k * 8) * 16 + l15;      // 0..511
        int gy = y0 + (q >> 7), gx = q & 127;
        #pragma unroll
        for (int kk = 0; kk < 8; ++kk) {
            int kidx = kg * 8 + kk;
            unsigned short v = 0;
            if (kidx < 18) {
                int ch = (kidx >= 9) ? 1 : 0;
                int km = kidx - ch * 9;
                int ky = km / 3, kx = km - ky * 3;
                int yy = gy + ky - 1, xx = gx + kx - 1;
                if ((unsigned)yy < 128u && (unsigned)xx < 128u)
                    v = bfbits((ch ? in1 : in0)[yy * W_ + xx]);
            }
            f[kk] = (short)v;
        }
        bfrag[k] = f;
    }
    __syncthreads();

    #pragma unroll
    for (int cc = 0; cc < 4; ++cc) {
        short8 a1 = *(const short8*)&w1l[(cc * 32 + wm * 16 + l15) * 32 + kg * 8];
        float ls[4] = {0.f, 0.f, 0.f, 0.f}, lq[4] = {0.f, 0.f, 0.f, 0.f};
        #pragma unroll
        for (int k = 0; k < 4; ++k) {
            f32x4 hacc = (f32x4){0.f, 0.f, 0.f, 0.f};
            hacc = __builtin_amdgcn_mfma_f32_16x16x32_bf16(a1, bfrag[k], hacc, 0, 0, 0);
            #pragma unroll
            for (int rr = 0; rr < 4; ++rr) {
                float h = hacc[rr] + b1sh[cc * 32 + wm * 16 + kg * 4 + rr];
                ls[rr] += h; lq[rr] += h * h;
            }
        }
        #pragma unroll
        for (int rr = 0; rr < 4; ++rr) {
            #pragma unroll
            for (int m = 1; m < 16; m <<= 1) {
                ls[rr] += __shfl_xor(ls[rr], m, 64);
                lq[rr] += __shfl_xor(lq[rr], m, 64);
            }
            if (l15 == 0) {
                int ci = cc * 32 + wm * 16 + kg * 4 + rr;
                atomicAdd(&redS[ci], ls[rr]);
                atomicAdd(&redQ[ci], lq[rr]);
            }
        }
    }
    __syncthreads();
    if (tid < 128) { atomicAdd(&sum1[tid], redS[tid]); atomicAdd(&sq1[tid], redQ[tid]); }
}

// ---------------- conv2 via MFMA: GOLDEN r6 structure + inline BN1 (r12-exact) ----------
__global__ __launch_bounds__(1024) void conv2_mfma(
    const float* __restrict__ out5,
    const float* __restrict__ b1,
    const float* __restrict__ g1,
    const float* __restrict__ be1,
    const float* __restrict__ sum1,
    const float* __restrict__ sq1,
    const unsigned short* __restrict__ w2t2,
    const unsigned short* __restrict__ w1t,
    const float* __restrict__ b2,
    __hip_bfloat16* __restrict__ y2,
    float* __restrict__ sum2,
    float* __restrict__ sq2)
{
    __shared__ unsigned short inT[31200];
    __shared__ unsigned short wc[36864];
    __shared__ unsigned short w1l[4096];
    __shared__ float s1sh[128], t1sh[128], redS[128], redQ[128];

    const int tid = threadIdx.x;
    const int b  = blockIdx.x >> 5;
    const int y0 = (blockIdx.x & 31) * 4;
    const int lane = tid & 63, w = tid >> 6;
    const int wm = w & 1, wn = w >> 1;
    const int l15 = lane & 15, kg = lane >> 4;

    if (tid < 128) {
        redS[tid] = 0.f; redQ[tid] = 0.f;
        const float N = (float)(B_ * HW_);
        float m = sum1[tid] / N;
        float v = sq1[tid] / N - m * m;
        float sc = g1[tid] / sqrtf(v + 1e-5f);
        s1sh[tid] = sc;
        t1sh[tid] = fmaf(sc, b1[tid] - m, be1[tid]);
    }
    if (tid < 512) *(short8*)&w1l[tid * 8] = *(const short8*)&w1t[tid * 8];

    const float* in0 = out5 + (size_t)b * 5 * HW_;
    const float* in1 = in0 + HW_;
    const int mi  = wm;
    const int njb = w >> 1;
    short8 bfrag[7];
    #pragma unroll
    for (int k = 0; k < 7; ++k) {
        short8 f = (short8){0,0,0,0,0,0,0,0};
        int nj = njb + k * 8;
        int q  = nj * 16 + l15;
        if (nj <= 48 && q < 780) {
            int r = q / 130, c = q - r * 130;
            int gy = y0 - 1 + r, gx = c - 1;
            #pragma unroll
            for (int kk = 0; kk < 8; ++kk) {
                int kidx = kg * 8 + kk;
                unsigned short v = 0;
                if (kidx < 18) {
                    int ch = (kidx >= 9) ? 1 : 0;
                    int km = kidx - ch * 9;
                    int ky = km / 3, kx = km - ky * 3;
                    int yy = gy + ky - 1, xx = gx + kx - 1;
                    if ((unsigned)yy < 128u && (unsigned)xx < 128u)
                        v = bfbits((ch ? in1 : in0)[yy * W_ + xx]);
                }
                f[kk] = (short)v;
            }
        }
        bfrag[k] = f;
    }
    __syncthreads();

    f32x4 acc[4][4];
    #pragma unroll
    for (int fm = 0; fm < 4; ++fm)
        #pragma unroll
        for (int fn = 0; fn < 4; ++fn) acc[fm][fn] = (f32x4){0.f, 0.f, 0.f, 0.f};

    for (int cc = 0; cc < 4; ++cc) {
        const unsigned short* wsrc = w2t2 + cc * 36864;
        #pragma unroll
        for (int u = 0; u < 4; ++u)
            __builtin_amdgcn_global_load_lds(
                (const unsigned int*)(wsrc + (u * 1024 + tid) * 8),
                (unsigned int*)&wc[(u * 1024 + tid) * 8], 16, 0, 0);
        if (tid < 512)
            __builtin_amdgcn_global_load_lds(
                (const unsigned int*)(wsrc + (4096 + tid) * 8),
                (unsigned int*)&wc[(4096 + tid) * 8], 16, 0, 0);

        short8 a1 = *(const short8*)&w1l[(cc * 32 + mi * 16 + l15) * 32 + kg * 8];
        #pragma unroll
        for (int k = 0; k < 7; ++k) {
            int nj = njb + k * 8;
            if (nj <= 48) {
                int q = nj * 16 + l15;
                f32x4 hacc = (f32x4){0.f, 0.f, 0.f, 0.f};
                hacc = __builtin_amdgcn_mfma_f32_16x16x32_bf16(a1, bfrag[k], hacc, 0, 0, 0);
                int r = q / 130, c = q - r * 130;
                int gy = y0 - 1 + r;
                bool zero = (q >= 780) || ((unsigned)gy >= 128u) || (c == 0) || (c == 129);
                short4v hv;
                #pragma unroll
                for (int rr = 0; rr < 4; ++rr) {
                    int cig = cc * 32 + mi * 16 + kg * 4 + rr;
                    float h = fmaxf(fmaf(s1sh[cig], hacc[rr], t1sh[cig]), 0.f);
                    hv[rr] = zero ? (short)0 : (short)bfbits(h);
                }
                if (q < 780)
                    *(short4v*)&inT[(r * 130 + c) * 40 + mi * 16 + kg * 4] = hv;
            }
        }
        __syncthreads();

        #pragma unroll
        for (int kk = 0; kk < 9; ++kk) {
            const int ky = kk / 3, kx = kk % 3;
            short8 af[4], bfv[4];
            #pragma unroll
            for (int fm = 0; fm < 4; ++fm)
                af[fm] = *(const short8*)&wc[((kk * 4 + kg) * 128 + wm * 64 + fm * 16 + l15) * 8];
            #pragma unroll
            for (int fn = 0; fn < 4; ++fn) {
                int n = wn * 64 + fn * 16 + l15;
                int r = (n >> 7) + ky, c2 = (n & 127) + kx;
                bfv[fn] = *(const short8*)&inT[(r * 130 + c2) * 40 + kg * 8];
            }
            #pragma unroll
            for (int fm = 0; fm < 4; ++fm)
                #pragma unroll
                for (int fn = 0; fn < 4; ++fn)
                    acc[fm][fn] = __builtin_amdgcn_mfma_f32_16x16x32_bf16(af[fm], bfv[fn], acc[fm][fn], 0, 0, 0);
        }
        __syncthreads();
    }

    unsigned short* pt = wc;
    #pragma unroll
    for (int fm = 0; fm < 4; ++fm) {
        #pragma unroll
        for (int r = 0; r < 4; ++r) {
            const int col = fm * 16 + kg * 4 + r;
            const int co  = wm * 64 + col;
            const float bb = b2[co];
            float ls = 0.f, lq = 0.f;
            #pragma unroll
            for (int fn = 0; fn < 4; ++fn) {
                float v = acc[fm][fn][r] + bb;
                ls += v; lq += v * v;
            }
            #pragma unroll
            for (int m = 1; m < 16; m <<= 1) {
                ls += __shfl_xor(ls, m, 64);
                lq += __shfl_xor(lq, m, 64);
            }
            if (l15 == 0) { atomicAdd(&redS[co], ls); atomicAdd(&redQ[co], lq); }
        }
    }
    if (wm == 0) {
        #pragma unroll
        for (int fm = 0; fm < 4; ++fm)
            #pragma unroll
            for (int r = 0; r < 4; ++r) {
                const int col = fm * 16 + kg * 4 + r;
                const float bb = b2[col];
                const int xr = ((col >> 2) & 3) << 4;
                #pragma unroll
                for (int fn = 0; fn < 4; ++fn) {
                    int n = wn * 64 + fn * 16 + l15;
                    pt[col * 512 + (n ^ xr)] = bfbits(acc[fm][fn][r] + bb);
                }
            }
    }
    __syncthreads();
    if (tid < 128) { atomicAdd(&sum2[tid], redS[tid]); atomicAdd(&sq2[tid], redQ[tid]); }
    {
        unsigned short* y2u = (unsigned short*)y2;
        int co_l = tid >> 4, sub = tid & 15;
        int xr = ((co_l >> 2) & 3) << 4;
        size_t base = (((size_t)b * C1_ + co_l) * H_ + y0) * (size_t)W_ + sub * 8;
        #pragma unroll
        for (int j = 0; j < 4; ++j) {
            int p = j * 128 + sub * 8;
            *(short8*)&y2u[base + (size_t)j * W_] = *(short8*)&pt[co_l * 512 + (p ^ xr)];
        }
    }
    __syncthreads();
    if (wm == 1) {
        #pragma unroll
        for (int fm = 0; fm < 4; ++fm)
            #pragma unroll
            for (int r = 0; r < 4; ++r) {
                const int col = fm * 16 + kg * 4 + r;
                const float bb = b2[64 + col];
                const int xr = ((col >> 2) & 3) << 4;
                #pragma unroll
                for (int fn = 0; fn < 4; ++fn) {
                    int n = wn * 64 + fn * 16 + l15;
                    pt[col * 512 + (n ^ xr)] = bfbits(acc[fm][fn][r] + bb);
                }
            }
    }
    __syncthreads();
    {
        unsigned short* y2u = (unsigned short*)y2;
        int co_l = tid >> 4, sub = tid & 15;
        int xr = ((co_l >> 2) & 3) << 4;
        size_t base = (((size_t)b * C1_ + 64 + co_l) * H_ + y0) * (size_t)W_ + sub * 8;
        #pragma unroll
        for (int j = 0; j < 4; ++j) {
            int p = j * 128 + sub * 8;
            *(short8*)&y2u[base + (size_t)j * W_] = *(short8*)&pt[co_l * 512 + (p ^ xr)];
        }
    }
}

// ---------------- lateral path: maxpool2 + conv3x3(2->2) pad1 ----------------
__global__ __launch_bounds__(256) void poolconv_k(const float* __restrict__ out5,
                                                  const float* __restrict__ wl,
                                                  const float* __restrict__ bl,
                                                  float* __restrict__ ds) {
    int idx = blockIdx.x * 256 + threadIdx.x;
    int j = idx & 63;
    int i = (idx >> 6) & 63;
    int c = (idx >> 12) & 1;
    int b = idx >> 13;
    float acc = bl[c];
    #pragma unroll
    for (int ci = 0; ci < 2; ++ci) {
        const float* in = out5 + ((size_t)b * 5 + ci) * HW_;
        #pragma unroll
        for (int ky = 0; ky < 3; ++ky) {
            int ii = i + ky - 1;
            if (ii < 0 || ii > 63) continue;
            #pragma unroll
            for (int kx = 0; kx < 3; ++kx) {
                int jj = j + kx - 1;
                if (jj < 0 || jj > 63) continue;
                const float* p = in + (2 * ii) * W_ + 2 * jj;
                float pooled = fmaxf(fmaxf(p[0], p[1]), fmaxf(p[W_], p[W_ + 1]));
                acc += pooled * wl[(c * 2 + ci) * 9 + ky * 3 + kx];
            }
        }
    }
    ds[idx] = acc;
}

// ---------------- final: conv1x1(inline BN2+ReLU) + upsample + softmax + sigmoids, 8 px/thr ----
__global__ __launch_bounds__(256) void final_k(const float* __restrict__ out5,
                                               const __hip_bfloat16* __restrict__ y2,
                                               const float* __restrict__ g2,
                                               const float* __restrict__ be2,
                                               const float* __restrict__ sum2,
                                               const float* __restrict__ sq2,
                                               const float* __restrict__ w3,
                                               const float* __restrict__ b3,
                                               const float* __restrict__ dsb,
                                               float* __restrict__ out) {
    __shared__ float w3s[256], s2s[128], t2s[128];
    int tid = threadIdx.x;
    w3s[tid] = w3[tid];
    if (tid < 128) {
        const float N = (float)(B_ * HW_);
        float m = sum2[tid] / N;
        float v = sq2[tid] / N - m * m;
        float sc = g2[tid] / sqrtf(v + 1e-5f);
        s2s[tid] = sc;
        t2s[tid] = be2[tid] - sc * m;
    }
    __syncthreads();
    int gid = blockIdx.x * 256 + tid;       // 65536 threads, 8 px each
    int b = gid >> 11;
    int rem = gid & 2047;
    int y = rem >> 4;
    int x0 = (rem & 15) * 8;
    int p = y * W_ + x0;

    const unsigned short* yp = (const unsigned short*)y2 + (size_t)b * C1_ * HW_ + p;
    float jm0[8], jm1[8];
    #pragma unroll
    for (int i = 0; i < 8; ++i) { jm0[i] = b3[0]; jm1[i] = b3[1]; }
    for (int ci = 0; ci < 128; ++ci) {
        short8 v = *(const short8*)(yp + (size_t)ci * HW_);
        float sc = s2s[ci], tc = t2s[ci];
        float w0 = w3s[ci], w1c = w3s[128 + ci];
        #pragma unroll
        for (int i = 0; i < 8; ++i) {
            float h = fmaxf(fmaf(sc, bf2f((unsigned short)v[i]), tc), 0.f);
            jm0[i] = fmaf(h, w0, jm0[i]);
            jm1[i] = fmaf(h, w1c, jm1[i]);
        }
    }

    const float fo = (float)(63.0 / 127.0);
    float sy = (float)y * fo;
    int ly = (int)floorf(sy); ly = ly < 0 ? 0 : (ly > 62 ? 62 : ly);
    float wy = sy - (float)ly;
    const float* dbase = dsb + ((size_t)b * 2) * 4096;
    float sig[8];
    #pragma unroll
    for (int i = 0; i < 8; ++i) {
        int x = x0 + i;
        float sx = (float)x * fo;
        int lx = (int)floorf(sx); lx = lx < 0 ? 0 : (lx > 62 ? 62 : lx);
        float wx = sx - (float)lx;
        float up[2];
        #pragma unroll
        for (int c = 0; c < 2; ++c) {
            const float* d = dbase + c * 4096;
            float d00 = d[ly * 64 + lx],       d01 = d[ly * 64 + lx + 1];
            float d10 = d[(ly + 1) * 64 + lx], d11 = d[(ly + 1) * 64 + lx + 1];
            up[c] = (1.f - wy) * ((1.f - wx) * d00 + wx * d01) + wy * ((1.f - wx) * d10 + wx * d11);
        }
        float dlt = (jm1[i] + up[1]) - (jm0[i] + up[0]);
        sig[i] = 1.f / (1.f + expf(-dlt));
    }
    *(f32x4*)&out[(size_t)b * HW_ + p]     = (f32x4){sig[0], sig[1], sig[2], sig[3]};
    *(f32x4*)&out[(size_t)b * HW_ + p + 4] = (f32x4){sig[4], sig[5], sig[6], sig[7]};

    #pragma unroll
    for (int h2 = 0; h2 < 2; ++h2) {
        f32x4 lm = *(const f32x4*)&out5[((size_t)b * 5 + 2) * HW_ + p + h2 * 4];
        f32x4 r;
        #pragma unroll
        for (int i = 0; i < 4; ++i) r[i] = 1.f / (1.f + expf(-lm[i]));
        *(f32x4*)&out[524288 + (size_t)b * HW_ + p + h2 * 4] = r;
    }
    #pragma unroll
    for (int h2 = 0; h2 < 2; ++h2) {
        f32x4 o3 = *(const f32x4*)&out5[((size_t)b * 5 + 3) * HW_ + p + h2 * 4];
        f32x4 o4 = *(const f32x4*)&out5[((size_t)b * 5 + 4) * HW_ + p + h2 * 4];
        f32x4 r3, r4;
        #pragma unroll
        for (int i = 0; i < 4; ++i) {
            r3[i] = 1.f / (1.f + expf(-o3[i])) - 0.5f;
            r4[i] = 1.f / (1.f + expf(-o4[i])) - 0.5f;
        }
        *(f32x4*)&out[1048576 + ((size_t)b * 2 + 0) * HW_ + p + h2 * 4] = r3;
        *(f32x4*)&out[1048576 + ((size_t)b * 2 + 1) * HW_ + p + h2 * 4] = r4;
    }
}

extern "C" void kernel_launch(void* const* d_in, const int* in_sizes, int n_in,
                              void* d_out, int out_size, void* d_ws, size_t ws_size,
                              hipStream_t stream) {
    const float* out5 = (const float*)d_in[0];
    const float* jmap = (const float*)d_in[1];
    const float* w1   = (const float*)d_in[2];
    const float* b1   = (const float*)d_in[3];
    const float* g1   = (const float*)d_in[4];
    const float* be1  = (const float*)d_in[5];
    const float* w2   = (const float*)d_in[6];
    const float* b2   = (const float*)d_in[7];
    const float* g2   = (const float*)d_in[8];
    const float* be2  = (const float*)d_in[9];
    const float* w3   = (const float*)d_in[10];
    const float* b3   = (const float*)d_in[11];
    const float* wl   = (const float*)d_in[12];
    const float* bl   = (const float*)d_in[13];
    const float* ga   = (const float*)d_in[14];
    const float* gb   = (const float*)d_in[15];
    float* out = (float*)d_out;

    // ws layout (~135.3 MB):
    //   [0, 134217728)           y2 bf16
    //   [134217728, +294912)     w2t2 } overlapped later by dsb (disjoint lifetimes)
    //   [134512640, +8192)       w1t  }
    //   [134217728, +1048576)    dsb (poolconv out; written after conv2 done)
    //   [135266304, +4096)       stats
    char* ws = (char*)d_ws;
    __hip_bfloat16* y2 = (__hip_bfloat16*)ws;
    unsigned short* w2t2 = (unsigned short*)(ws + 134217728);
    unsigned short* w1t  = (unsigned short*)(ws + 134512640);
    float* dsb = (float*)(ws + 134217728);
    float* st  = (float*)(ws + 135266304);
    float* sum1 = st;        float* sq1 = st + 128;
    float* sum2 = st + 256;  float* sq2 = st + 384;

    float* gout = out + 2097152;   // gauss target region of d_out

    prep_gauss<<<2642, 256, 0, stream>>>(w2, w1, w2t2, w1t, st, jmap, gout, ga, gb);
    conv1stats_mfma<<<1024, 1024, 0, stream>>>(out5, b1, w1t, sum1, sq1);
    conv2_mfma<<<1024, 1024, 0, stream>>>(out5, b1, g1, be1, sum1, sq1, w2t2, w1t, b2, y2, sum2, sq2);
    poolconv_k<<<1024, 256, 0, stream>>>(out5, wl, bl, dsb);
    final_k<<<256, 256, 0, stream>>>(out5, y2, g2, be2, sum2, sq2, w3, b3, dsb, out);
}